// Round 11
// baseline (1188.649 us; speedup 1.0000x reference)
//
#include <hip/hip_runtime.h>
#include <math.h>

// Problem dims (fixed by the reference file)
#define DHID 128
#define DXIN 16
#define DIN  144   // DHID + DXIN
#define G3   384   // 3*DHID
#define NLEV 16
#define SCAN_CHUNK 2048
#define KP   160   // GEMM1 K padded to mult of 32
#define AS   168   // A LDS row stride in bf16 units
#define HS   136   // H LDS row stride in bf16 units
#define TN   64    // tile nodes
#define GRID 256
#define BLK  512

typedef __attribute__((ext_vector_type(8))) short short8_t;
typedef __attribute__((ext_vector_type(4))) float f32x4;

__device__ __forceinline__ float sigmoidf_(float v){ return 1.0f/(1.0f + __expf(-v)); }
__device__ __forceinline__ float tanhf_(float v){
  v = fminf(fmaxf(v,-15.f),15.f);
  float e = __expf(2.f*v);
  return (e-1.f)/(e+1.f);
}
__device__ __forceinline__ unsigned short f2bf(float f){
  unsigned u = __float_as_uint(f);
  u = u + 0x7FFFu + ((u>>16)&1u);
  return (unsigned short)(u>>16);
}
__device__ __forceinline__ float bf2f(unsigned short h){
  return __uint_as_float(((unsigned)h)<<16);
}

// coherent (device-scope, L2-bypass) 64B store
__device__ __forceinline__ void row_store_coh(float* p,
                                              f32x4 v0, f32x4 v1, f32x4 v2, f32x4 v3){
  asm volatile(
    "global_store_dwordx4 %0, %1, off sc0 sc1\n\t"
    "global_store_dwordx4 %0, %2, off offset:16 sc0 sc1\n\t"
    "global_store_dwordx4 %0, %3, off offset:32 sc0 sc1\n\t"
    "global_store_dwordx4 %0, %4, off offset:48 sc0 sc1"
    :: "v"(p), "v"(v0), "v"(v1), "v"(v2), "v"(v3)
    : "memory");
}
// coherent 64B load ISSUE only (no wait) — caller does one vmcnt(0) per batch
__device__ __forceinline__ void row_load_issue(const float* p,
                                               f32x4& v0, f32x4& v1, f32x4& v2, f32x4& v3){
  asm volatile(
    "global_load_dwordx4 %0, %4, off sc0 sc1\n\t"
    "global_load_dwordx4 %1, %4, off offset:16 sc0 sc1\n\t"
    "global_load_dwordx4 %2, %4, off offset:32 sc0 sc1\n\t"
    "global_load_dwordx4 %3, %4, off offset:48 sc0 sc1"
    : "=&v"(v0), "=&v"(v1), "=&v"(v2), "=&v"(v3)
    : "v"(p));
}

// ---------------- zero counters / indeg / fill / level counters ----------------
__global__ void k_zero0(int* ints, int* lvl_cnt, int* indeg, int* fill, int N){
  int i = blockIdx.x*blockDim.x + threadIdx.x;
  int stride = gridDim.x*blockDim.x;
  if(i<1024) ints[i]=0;
  if(i<2048) lvl_cnt[i]=0;
  for(int j=i;j<N;j+=stride){ indeg[j]=0; fill[j]=0; }
}

// ---------------- precompute h_init, t_init, gh_init, c0 ----------------
// consts (floats): [0..127]=h_init [128..255]=t_init [256..639]=gh(r,z,n) [640]=c0
__global__ void k_init(const float* emd_w, const float* emd_b,
                       const float* agg_w, const float* agg_b,
                       const float* w_hh, const float* b_hh,
                       const float* w1,const float* b1,const float* w2,const float* b2,
                       const float* w3,const float* b3,
                       float* consts){
  __shared__ float hl[128];
  __shared__ float z1[32];
  __shared__ float z2[32];
  int t = threadIdx.x;
  float h = emd_w[t] + emd_b[t];
  hl[t] = h; consts[t] = h;
  __syncthreads();
  float s = agg_b[t];
  for(int k=0;k<128;k++) s += agg_w[t*128+k]*hl[k];
  consts[128+t] = s;
  for(int g=t; g<G3; g+=128){
    float q = b_hh[g];
    for(int k=0;k<128;k++) q += w_hh[g*128+k]*hl[k];
    consts[256+g] = q;
  }
  if(t<32){
    float a = b1[t];
    for(int k=0;k<128;k++) a += w1[t*128+k]*hl[k];
    z1[t] = fmaxf(a,0.f);
  }
  __syncthreads();
  if(t<32){
    float a = b2[t];
    for(int k=0;k<32;k++) a += w2[t*32+k]*z1[k];
    z2[t] = fmaxf(a,0.f);
  }
  __syncthreads();
  if(t==0){
    float a = b3[0];
    for(int k=0;k<32;k++) a += w3[k]*z2[k];
    consts[640] = a;
  }
}

// ---------------- split weights into bf16 hi/lo ----------------
__global__ void k_wprep(const float* w_ih, const float* agg_w, const float* w1,
                        unsigned short* wih_h, unsigned short* wih_l,
                        unsigned short* agg_h, unsigned short* agg_l,
                        unsigned short* w1_h, unsigned short* w1_l){
  int i = blockIdx.x*blockDim.x + threadIdx.x;
  int stride = gridDim.x*blockDim.x;
  for(int idx=i; idx<G3*KP; idx+=stride){
    int g = idx/KP, k = idx - g*KP;
    float v = (k<DIN)? w_ih[g*DIN+k] : 0.f;
    unsigned short h = f2bf(v);
    wih_h[idx]=h; wih_l[idx]=f2bf(v-bf2f(h));
  }
  for(int idx=i; idx<DHID*DHID; idx+=stride){
    float v = agg_w[idx];
    unsigned short h=f2bf(v); agg_h[idx]=h; agg_l[idx]=f2bf(v-bf2f(h));
  }
  for(int idx=i; idx<32*DHID; idx+=stride){
    float v = w1[idx];
    unsigned short h=f2bf(v); w1_h[idx]=h; w1_l[idx]=f2bf(v-bf2f(h));
  }
}

// ---------------- node histogram by level ----------------
// ints: node_cnt@0(16) node_off@32(17) node_fill@64(16) tile_off@96(17)
__global__ void k_count(const int* fl, int N, int* ints){
  __shared__ int hn[16];
  int tid = threadIdx.x;
  if(tid<16) hn[tid]=0;
  __syncthreads();
  int i = blockIdx.x*blockDim.x+tid;
  int stride = gridDim.x*blockDim.x;
  for(int j=i;j<N;j+=stride) atomicAdd(&hn[fl[j]], 1);
  __syncthreads();
  if(tid<16 && hn[tid]) atomicAdd(&ints[tid], hn[tid]);
}

__global__ void k_prefix(int* ints){
  if(threadIdx.x==0 && blockIdx.x==0){
    int o=0;
    for(int l=0;l<NLEV;l++){ ints[32+l]=o; ints[64+l]=o; o+=ints[l]; }
    ints[32+NLEV]=o;
    int to=0;
    ints[96]=0;
    for(int l=1;l<NLEV;l++){ ints[96+l]=to; to += (ints[l]+TN-1)/TN; }
    ints[96+NLEV]=to;   // total tiles
  }
}

// Two-pass per-block counting sort of nodes by level.
__global__ void k_build(const int* fl, int N, int* ints,
                        int* node_list, int* node_rank){
  __shared__ int h[16], base[16];
  int tid = threadIdx.x;
  int nchunk = (N + gridDim.x - 1)/gridDim.x;
  int lo = blockIdx.x*nchunk;
  int hi = lo + nchunk; if(hi>N) hi=N;
  if(tid<16) h[tid]=0;
  __syncthreads();
  for(int j=lo+tid; j<hi; j+=blockDim.x) atomicAdd(&h[fl[j]],1);
  __syncthreads();
  if(tid<16){ base[tid] = h[tid] ? atomicAdd(&ints[64+tid], h[tid]) : 0; h[tid]=0; }
  __syncthreads();
  for(int j=lo+tid; j<hi; j+=blockDim.x){
    int lev = fl[j];
    int pos = base[lev] + atomicAdd(&h[lev],1);
    node_list[pos]=j;
    node_rank[j]=pos-ints[32+lev];
  }
}

// ---------------- indegree histogram over permuted node positions ----------------
__global__ void k_indeg(const int* ei, const int* fl, const int* node_rank,
                        const int* ints, int* indeg, int E){
  int i = blockIdx.x*blockDim.x+threadIdx.x;
  int stride = gridDim.x*blockDim.x;
  for(int e=i;e<E;e+=stride){
    int tg = ei[E+e];
    int p = ints[32+fl[tg]] + node_rank[tg];
    atomicAdd(&indeg[p],1);
  }
}

// ---------------- hierarchical exclusive scan of indeg -> row_ptr ----------------
__global__ void k_scan_a(const int* indeg, int* bsum, int N){
  __shared__ int ts[256];
  int b=blockIdx.x, t=threadIdx.x;
  int base=b*SCAN_CHUNK+t*8; int s=0;
  for(int j=0;j<8;j++){ int idx=base+j; if(idx<N) s+=indeg[idx]; }
  ts[t]=s; __syncthreads();
  for(int off=128;off>0;off>>=1){ if(t<off) ts[t]+=ts[t+off]; __syncthreads(); }
  if(t==0) bsum[b]=ts[0];
}
__global__ void k_scan_b(int* bsum, int nb){
  __shared__ int ls[256];
  int t=threadIdx.x;
  int v = (t<nb)? bsum[t]:0; ls[t]=v; __syncthreads();
  for(int off=1;off<256;off<<=1){
    int add = (t>=off)? ls[t-off]:0;
    __syncthreads();
    ls[t]+=add;
    __syncthreads();
  }
  if(t<nb) bsum[t] = ls[t]-v;   // exclusive
}
__global__ void k_scan_c(const int* indeg, const int* bsum, int* row_ptr, int N){
  __shared__ int ts[256];
  int b=blockIdx.x, t=threadIdx.x;
  int base=b*SCAN_CHUNK+t*8;
  int v[8]; int s=0;
  for(int j=0;j<8;j++){ int idx=base+j; v[j]=(idx<N)?indeg[idx]:0; s+=v[j]; }
  ts[t]=s; __syncthreads();
  for(int off=1;off<256;off<<=1){
    int add = (t>=off)? ts[t-off]:0;
    __syncthreads();
    ts[t]+=add;
    __syncthreads();
  }
  int excl = bsum[b] + ((t>0)? ts[t-1]:0);
  for(int j=0;j<8;j++){ int idx=base+j; if(idx<N) row_ptr[idx]=excl; excl+=v[j]; }
}

// ------- place edges into CSR (level in bits 27+) -------
__global__ void k_place(const int* ei, const int* fl, const int* node_rank,
                        const int* ints, const int* row_ptr, int* fill,
                        int* edge_src, int E){
  int i = blockIdx.x*blockDim.x+threadIdx.x;
  int stride = gridDim.x*blockDim.x;
  for(int e=i;e<E;e+=stride){
    int s  = ei[e];
    int tg = ei[E+e];
    int p = ints[32+fl[tg]] + node_rank[tg];
    int slot = atomicAdd(&fill[p],1);
    edge_src[row_ptr[p]+slot] = s | (fl[s]<<27);
  }
}

// ---------------- out = c0 for LEVEL-0 nodes only (never updated later) ---------
__global__ void k_outc(const int* node_list, const int* ints,
                       float* out, const float* consts){
  int cnt0 = ints[0];
  float c0 = consts[640];
  int i = blockIdx.x*blockDim.x+threadIdx.x;
  int stride = gridDim.x*blockDim.x;
  for(int j=i;j<cnt0;j+=stride) out[node_list[j]]=c0;
}

// ================= persistent kernel, coherent tbuf + per-level counters =========
// 256 blocks x 512 threads, 1 block/CU guaranteed. GEMM weights in registers.
// tbuf accessed ONLY via sc0|sc1 ops. Level arrival = ONE relaxed counter/level;
// waiter polls ONE relaxed load with backoff (no poll storm). Gather batches 4
// edges' loads before a single vmcnt(0) (one L3 round-trip per batch).
__global__ __launch_bounds__(BLK,2) void k_levels(
    const float* __restrict__ x, const int* __restrict__ node_list,
    const int* __restrict__ row_ptr, const int* __restrict__ indeg,
    const int* __restrict__ edge_src,
    float* __restrict__ tbuf,
    const unsigned short* __restrict__ wih_h, const unsigned short* __restrict__ wih_l,
    const unsigned short* __restrict__ agg_h, const unsigned short* __restrict__ agg_l,
    const unsigned short* __restrict__ w1_h, const unsigned short* __restrict__ w1_l,
    const float* __restrict__ b_ih, const float* __restrict__ agg_b,
    const float* __restrict__ b1, const float* __restrict__ w2,
    const float* __restrict__ b2, const float* __restrict__ w3,
    const float* __restrict__ b3,
    const float* __restrict__ consts, float* __restrict__ out,
    int* ints, int* lvl_cnt)
{
  __shared__ __align__(16) unsigned char smem[64256];
  unsigned short* Ahi = (unsigned short*)smem;
  unsigned short* Alo = (unsigned short*)(smem + 21504);
  unsigned short* Hhi = (unsigned short*)smem;
  unsigned short* Hlo = (unsigned short*)(smem + 17408);
  float* tst = (float*)smem;                 // [64][132]
  float* z1l = (float*)(smem + 43008);
  float* z2l = (float*)(smem + 51456);
  float* w2t = (float*)(smem + 59904);
  float* w3l = (float*)(smem + 64128);

  int tid = threadIdx.x;
  int wv = tid>>6, ln = tid&63, lr = ln&15, lq = ln>>4;
  int cgo = tid&7, nd = tid>>3;    // gather: 8 thr/node, 16 dims each
  int d = wv*16 + lr;              // this lane's output dim (GEMM1/2)
  int mB = wv>>1, nB = wv&1;       // MLP1 sub-tile

  // ---- persistent weight fragments (w_ih + agg) ----
  short8_t wfh[15], wfl[15];
  #pragma unroll
  for(int g=0;g<3;g++)
    #pragma unroll
    for(int kk=0;kk<5;kk++){
      long long ro = (long long)(g*128 + d)*KP + kk*32 + lq*8;
      wfh[g*5+kk] = *(const short8_t*)&wih_h[ro];
      wfl[g*5+kk] = *(const short8_t*)&wih_l[ro];
    }
  short8_t agh[4], agl[4];
  #pragma unroll
  for(int kk=0;kk<4;kk++){
    int ro = d*DHID + kk*32 + lq*8;
    agh[kk] = *(const short8_t*)&agg_h[ro];
    agl[kk] = *(const short8_t*)&agg_l[ro];
  }
  float ghr=consts[256+d], ghz=consts[384+d], ghn=consts[512+d], h0c=consts[d];
  float bir=b_ih[d], biz=b_ih[128+d], bin_=b_ih[256+d], ab2=agg_b[d];
  float b1o = b1[nB*16+lr];
  f32x4 ti[4];
  { const f32x4* c4=(const f32x4*)(consts+128);
    #pragma unroll
    for(int q=0;q<4;q++) ti[q]=c4[cgo*4+q]; }

  // ---- stage small fp32 weights ----
  for(int idx=tid; idx<1024; idx+=BLK){ int j=idx>>5, k=idx&31;  w2t[k*33+j]=w2[idx]; }
  if(tid<32) w3l[tid]=w3[tid];
  __syncthreads();

  int total_tiles = ints[96+NLEV];
  int l = 1;

  for(int T = blockIdx.x; T < total_tiles; T += GRID){
    while(l < NLEV-1 && T >= ints[96+l+1]) l++;
    int cnt  = ints[l];
    int base = ints[32+l];
    int n0 = (T - ints[96+l])*TN;

    // ---- x into A cols 128..143, zero 144..159 (pre-wait; no tbuf access) ----
    if(tid<256){
      int i = tid>>2, j = tid&3;
      int gi = n0+i;
      float4 xv = make_float4(0.f,0.f,0.f,0.f);
      if(gi<cnt) xv = ((const float4*)x)[node_list[base+gi]*4 + j];
      float vv[4]={xv.x,xv.y,xv.z,xv.w};
      #pragma unroll
      for(int q=0;q<4;q++){
        unsigned short h=f2bf(vv[q]);
        Ahi[i*AS+128+j*4+q]=h;
        Alo[i*AS+128+j*4+q]=f2bf(vv[q]-bf2f(h));
      }
      #pragma unroll
      for(int q=0;q<4;q++){ Ahi[i*AS+144+j*4+q]=0; Alo[i*AS+144+j*4+q]=0; }
    }

    // ---- wait: previous level fully done (single counter, backoff poll) ----
    if(tid==0 && l>1){
      int need = ints[96+l] - ints[96+l-1];
      if(need>0){
        int it=0;
        while(__hip_atomic_load(&lvl_cnt[(l-1)*32], __ATOMIC_RELAXED,
                                __HIP_MEMORY_SCOPE_AGENT) < need){
          if(it<8) __builtin_amdgcn_s_sleep(8);
          else     __builtin_amdgcn_s_sleep(32);
          it++;
        }
      }
    }
    __syncthreads();

    // ---- phase 0: gather msg (batched coherent loads) -> bf16 hi/lo into A ----
    {
      f32x4 a[4];
      #pragma unroll
      for(int q=0;q<4;q++) a[q]=(f32x4){0.f,0.f,0.f,0.f};
      int gi = n0+nd;
      if(gi<cnt){
        int p = base+gi;
        int r0 = row_ptr[p], deg = indeg[p];
        if(l==1){
          float fd = (float)deg;
          #pragma unroll
          for(int q=0;q<4;q++) a[q] = fd*ti[q];
        } else {
          int e = 0;
          while(e < deg){
            int nb4 = deg - e; if(nb4 > 4) nb4 = 4;
            f32x4 vr0[4], vr1[4], vr2[4], vr3[4];
            bool isrow[4];
            #pragma unroll
            for(int q=0;q<4;q++){
              isrow[q] = false;
              if(q < nb4){
                int pk = edge_src[r0+e+q];
                int fls = ((unsigned)pk)>>27;
                int s = pk & 0x07FFFFFF;
                if(fls>=1 && fls<l){
                  isrow[q] = true;
                  const float* sp = tbuf + ((long long)s*128 + cgo*16);
                  row_load_issue(sp, vr0[q], vr1[q], vr2[q], vr3[q]);
                } else {
                  a[0]+=ti[0]; a[1]+=ti[1]; a[2]+=ti[2]; a[3]+=ti[3];
                }
              }
            }
            asm volatile("s_waitcnt vmcnt(0)" ::: "memory");
            __builtin_amdgcn_sched_barrier(0);
            #pragma unroll
            for(int q=0;q<4;q++){
              if(isrow[q]){
                a[0]+=vr0[q]; a[1]+=vr1[q]; a[2]+=vr2[q]; a[3]+=vr3[q];
              }
            }
            e += nb4;
          }
        }
      }
      #pragma unroll
      for(int hf=0; hf<2; hf++){
        short8_t hv, lv;
        #pragma unroll
        for(int j=0;j<8;j++){
          float v = a[hf*2 + (j>>2)][j&3];
          unsigned short h = f2bf(v);
          hv[j]=(short)h; lv[j]=(short)f2bf(v-bf2f(h));
        }
        *(short8_t*)&Ahi[nd*AS + cgo*16 + hf*8] = hv;
        *(short8_t*)&Alo[nd*AS + cgo*16 + hf*8] = lv;
      }
    }
    __syncthreads();   // sync1: A ready

    // ---- prefetch w1 fragments (used in phase 3; hides under GEMM1) ----
    short8_t w1fh[4], w1fl[4];
    #pragma unroll
    for(int kk=0;kk<4;kk++){
      int ro = (nB*16+lr)*DHID + kk*32 + lq*8;
      w1fh[kk] = *(const short8_t*)&w1_h[ro];
      w1fl[kk] = *(const short8_t*)&w1_l[ro];
    }

    // ---- phase 1: GEMM1 (bf16x3 MFMA, weights in regs), 4 node-blocks ----
    f32x4 Ar[4],Az[4],An[4];
    #pragma unroll
    for(int m=0;m<4;m++){
      Ar[m]=(f32x4){bir,bir,bir,bir};
      Az[m]=(f32x4){biz,biz,biz,biz};
      An[m]=(f32x4){bin_,bin_,bin_,bin_};
    }
    #pragma unroll
    for(int kk=0;kk<5;kk++){
      short8_t ah[4], al[4];
      #pragma unroll
      for(int m=0;m<4;m++){
        int off = (m*16+lr)*AS + kk*32 + lq*8;
        ah[m]=*(const short8_t*)&Ahi[off];
        al[m]=*(const short8_t*)&Alo[off];
      }
      #pragma unroll
      for(int m=0;m<4;m++){
        Ar[m]=__builtin_amdgcn_mfma_f32_16x16x32_bf16(ah[m],wfh[kk],   Ar[m],0,0,0);
        Ar[m]=__builtin_amdgcn_mfma_f32_16x16x32_bf16(ah[m],wfl[kk],   Ar[m],0,0,0);
        Ar[m]=__builtin_amdgcn_mfma_f32_16x16x32_bf16(al[m],wfh[kk],   Ar[m],0,0,0);
        Az[m]=__builtin_amdgcn_mfma_f32_16x16x32_bf16(ah[m],wfh[5+kk], Az[m],0,0,0);
        Az[m]=__builtin_amdgcn_mfma_f32_16x16x32_bf16(ah[m],wfl[5+kk], Az[m],0,0,0);
        Az[m]=__builtin_amdgcn_mfma_f32_16x16x32_bf16(al[m],wfh[5+kk], Az[m],0,0,0);
        An[m]=__builtin_amdgcn_mfma_f32_16x16x32_bf16(ah[m],wfh[10+kk],An[m],0,0,0);
        An[m]=__builtin_amdgcn_mfma_f32_16x16x32_bf16(ah[m],wfl[10+kk],An[m],0,0,0);
        An[m]=__builtin_amdgcn_mfma_f32_16x16x32_bf16(al[m],wfh[10+kk],An[m],0,0,0);
      }
    }
    __syncthreads();   // sync2: all A reads done, H may overwrite

    // ---- phase 2: GRU gates -> H (bf16 hi/lo over A region) ----
    #pragma unroll
    for(int m=0;m<4;m++){
      #pragma unroll
      for(int j=0;j<4;j++){
        float r = sigmoidf_(Ar[m][j] + ghr);
        float z = sigmoidf_(Az[m][j] + ghz);
        float n = tanhf_(An[m][j] + r*ghn);
        float h = (1.f-z)*n + z*h0c;
        int node = m*16 + lq*4 + j;
        unsigned short hb = f2bf(h);
        Hhi[node*HS + d] = hb;
        Hlo[node*HS + d] = f2bf(h - bf2f(hb));
      }
    }
    __syncthreads();   // sync3: H ready

    // ---- phase 3: GEMM2 (t, all waves) + MLP1 (z1, MFMA per-wave sub-tile) ----
    f32x4 T2[4];
    #pragma unroll
    for(int m=0;m<4;m++) T2[m]=(f32x4){ab2,ab2,ab2,ab2};
    f32x4 M1 = (f32x4){b1o,b1o,b1o,b1o};
    #pragma unroll
    for(int kk=0;kk<4;kk++){
      short8_t hh[4], hl2[4];
      #pragma unroll
      for(int m=0;m<4;m++){
        int off = (m*16+lr)*HS + kk*32 + lq*8;
        hh[m]=*(const short8_t*)&Hhi[off];
        hl2[m]=*(const short8_t*)&Hlo[off];
      }
      #pragma unroll
      for(int m=0;m<4;m++){
        T2[m]=__builtin_amdgcn_mfma_f32_16x16x32_bf16(hh[m], agh[kk],T2[m],0,0,0);
        T2[m]=__builtin_amdgcn_mfma_f32_16x16x32_bf16(hh[m], agl[kk],T2[m],0,0,0);
        T2[m]=__builtin_amdgcn_mfma_f32_16x16x32_bf16(hl2[m],agh[kk],T2[m],0,0,0);
      }
      M1=__builtin_amdgcn_mfma_f32_16x16x32_bf16(hh[mB], w1fh[kk],M1,0,0,0);
      M1=__builtin_amdgcn_mfma_f32_16x16x32_bf16(hh[mB], w1fl[kk],M1,0,0,0);
      M1=__builtin_amdgcn_mfma_f32_16x16x32_bf16(hl2[mB],w1fh[kk],M1,0,0,0);
    }
    #pragma unroll
    for(int j=0;j<4;j++){
      int node = mB*16 + lq*4 + j;
      z1l[node*33 + nB*16+lr] = fmaxf(M1[j],0.f);
    }
    __syncthreads();   // sync4: H reads done; tst may overwrite; z1 ready

    // ---- phase 4: stage t into LDS (fp32) + MLP2 (VALU) ----
    #pragma unroll
    for(int m=0;m<4;m++){
      #pragma unroll
      for(int j=0;j<4;j++){
        int node = m*16 + lq*4 + j;
        tst[node*132 + d] = T2[m][j];
      }
    }
    {
      int ndl = tid>>3, jo = (tid&7)*4;
      float s0=b2[jo], s1=b2[jo+1], s2=b2[jo+2], s3=b2[jo+3];
      #pragma unroll 8
      for(int k=0;k<32;k++){
        float zv = z1l[ndl*33+k];
        s0 += zv*w2t[k*33+jo];
        s1 += zv*w2t[k*33+jo+1];
        s2 += zv*w2t[k*33+jo+2];
        s3 += zv*w2t[k*33+jo+3];
      }
      z2l[ndl*33+jo]   = fmaxf(s0,0.f);
      z2l[ndl*33+jo+1] = fmaxf(s1,0.f);
      z2l[ndl*33+jo+2] = fmaxf(s2,0.f);
      z2l[ndl*33+jo+3] = fmaxf(s3,0.f);
    }
    __syncthreads();   // sync5: tst + z2 ready

    // ---- phase 5: coherent t store + out store ----
    {
      int nd2 = tid>>3, q = tid&7;
      int gi = n0+nd2;
      if(gi<cnt){
        long long v = node_list[base+gi];
        float* dp = tbuf + v*128 + q*16;
        f32x4 v0 = *(const f32x4*)&tst[nd2*132 + q*16];
        f32x4 v1 = *(const f32x4*)&tst[nd2*132 + q*16 + 4];
        f32x4 v2 = *(const f32x4*)&tst[nd2*132 + q*16 + 8];
        f32x4 v3 = *(const f32x4*)&tst[nd2*132 + q*16 + 12];
        row_store_coh(dp, v0,v1,v2,v3);
      }
    }
    if(tid<TN){
      int gi = n0+tid;
      if(gi<cnt){
        float s = b3[0];
        #pragma unroll 8
        for(int k=0;k<32;k++) s += z2l[tid*33+k]*w3l[k];
        out[node_list[base+gi]] = s;
      }
    }
    __syncthreads();   // sync6: every wave drains vmcnt -> stores device-visible

    // ---- publish: one RELAXED add on this level's counter ----
    if(tid==0){
      asm volatile("s_waitcnt vmcnt(0)" ::: "memory");
      __hip_atomic_fetch_add(&lvl_cnt[l*32], 1, __ATOMIC_RELAXED,
                             __HIP_MEMORY_SCOPE_AGENT);
    }
  }
}

extern "C" void kernel_launch(void* const* d_in, const int* in_sizes, int n_in,
                              void* d_out, int out_size, void* d_ws, size_t ws_size,
                              hipStream_t stream){
  const float* x     = (const float*)d_in[0];
  const int*   ei    = (const int*)  d_in[1];
  const int*   fl    = (const int*)  d_in[2];
  const float* emd_w = (const float*)d_in[4];
  const float* emd_b = (const float*)d_in[5];
  const float* agg_w = (const float*)d_in[6];
  const float* agg_b = (const float*)d_in[7];
  const float* w_ih  = (const float*)d_in[8];
  const float* w_hh  = (const float*)d_in[9];
  const float* b_ih  = (const float*)d_in[10];
  const float* b_hh  = (const float*)d_in[11];
  const float* w1    = (const float*)d_in[12];
  const float* b1    = (const float*)d_in[13];
  const float* w2    = (const float*)d_in[14];
  const float* b2    = (const float*)d_in[15];
  const float* w3    = (const float*)d_in[16];
  const float* b3    = (const float*)d_in[17];
  float* out = (float*)d_out;

  int N = in_sizes[2];
  int E = in_sizes[1]/2;
  int nb = (N + SCAN_CHUNK - 1)/SCAN_CHUNK;

  char* ws = (char*)d_ws;
  float* consts   = (float*)ws;                    // 4 KiB
  int*   ints     = (int*)(ws + 4096);             // 4 KiB (tile_off@96)
  int*   node_list= (int*)(ws + 8192);
  int*   node_rank= node_list + N;
  int*   indeg    = node_rank + N;
  int*   row_ptr  = indeg + N;
  int*   fill     = row_ptr + N;
  int*   bsum     = fill + N;                      // 1024 block sums
  int*   lvl_cnt  = bsum + 1024;                   // 2048 (1 counter per level, spread)
  int*   edge_src = lvl_cnt + 2048;                // E ints (level in bits 27+)
  size_t off0 = 8192 + ((size_t)5*N + 1024 + 2048 + (size_t)E)*4;
  off0 = (off0 + 255) & ~(size_t)255;
  unsigned short* wih_h = (unsigned short*)(ws + off0);       // 384*160
  unsigned short* wih_l = wih_h + G3*KP;
  unsigned short* agg_h = wih_l + G3*KP;                      // 128*128
  unsigned short* agg_l = agg_h + DHID*DHID;
  unsigned short* w1_h  = agg_l + DHID*DHID;                  // 32*128
  unsigned short* w1_l  = w1_h + 32*DHID;
  size_t off1 = off0 + (size_t)(2*G3*KP + 2*DHID*DHID + 2*32*DHID)*2;
  off1 = (off1 + 255) & ~(size_t)255;
  float* tbuf = (float*)(ws + off1);               // N*128 floats, never pre-initialized
  size_t need = off1 + (size_t)N*128*4;
  if(ws_size < need) return;

  k_zero0  <<<512,256,0,stream>>>(ints, lvl_cnt, indeg, fill, N);
  k_init   <<<1,128,0,stream>>>(emd_w,emd_b,agg_w,agg_b,w_hh,b_hh,w1,b1,w2,b2,w3,b3,consts);
  k_wprep  <<<256,256,0,stream>>>(w_ih,agg_w,w1,wih_h,wih_l,agg_h,agg_l,w1_h,w1_l);
  k_count  <<<512,256,0,stream>>>(fl,N,ints);
  k_prefix <<<1,1,0,stream>>>(ints);
  k_build  <<<512,256,0,stream>>>(fl,N,ints,node_list,node_rank);
  k_indeg  <<<1024,256,0,stream>>>(ei,fl,node_rank,ints,indeg,E);
  k_scan_a <<<nb,256,0,stream>>>(indeg,bsum,N);
  k_scan_b <<<1,256,0,stream>>>(bsum,nb);
  k_scan_c <<<nb,256,0,stream>>>(indeg,bsum,row_ptr,N);
  k_place  <<<1024,256,0,stream>>>(ei,fl,node_rank,ints,row_ptr,fill,edge_src,E);
  k_outc   <<<256,256,0,stream>>>(node_list,ints,out,consts);
  k_levels <<<GRID,BLK,0,stream>>>(x,node_list,row_ptr,indeg,edge_src,tbuf,
                                   wih_h,wih_l,agg_h,agg_l,w1_h,w1_l,
                                   b_ih,agg_b,b1,w2,b2,w3,b3,
                                   consts,out,ints,lvl_cnt);
}

// Round 12
// 1013.356 us; speedup vs baseline: 1.1730x; 1.1730x over previous
//
#include <hip/hip_runtime.h>
#include <math.h>

// Problem dims (fixed by the reference file)
#define DHID 128
#define DXIN 16
#define DIN  144   // DHID + DXIN
#define G3   384   // 3*DHID
#define NLEV 16
#define SCAN_CHUNK 2048
#define KP   160   // GEMM1 K padded to mult of 32
#define AS   168   // A LDS row stride in bf16 units
#define HS   136   // H LDS row stride in bf16 units
#define TN   64    // tile nodes
#define GRID 256
#define BLK  512

typedef __attribute__((ext_vector_type(8))) short short8_t;
typedef __attribute__((ext_vector_type(4))) float f32x4;

__device__ __forceinline__ float sigmoidf_(float v){ return 1.0f/(1.0f + __expf(-v)); }
__device__ __forceinline__ float tanhf_(float v){
  v = fminf(fmaxf(v,-15.f),15.f);
  float e = __expf(2.f*v);
  return (e-1.f)/(e+1.f);
}
__device__ __forceinline__ unsigned short f2bf(float f){
  unsigned u = __float_as_uint(f);
  u = u + 0x7FFFu + ((u>>16)&1u);
  return (unsigned short)(u>>16);
}
__device__ __forceinline__ float bf2f(unsigned short h){
  return __uint_as_float(((unsigned)h)<<16);
}

// coherent (device-scope, L2-bypass) 64B row-quarter load (r9-proven, low-reg)
__device__ __forceinline__ void row_load_coh(const float* p,
                                             f32x4& v0, f32x4& v1, f32x4& v2, f32x4& v3){
  asm volatile(
    "global_load_dwordx4 %0, %4, off sc0 sc1\n\t"
    "global_load_dwordx4 %1, %4, off offset:16 sc0 sc1\n\t"
    "global_load_dwordx4 %2, %4, off offset:32 sc0 sc1\n\t"
    "global_load_dwordx4 %3, %4, off offset:48 sc0 sc1\n\t"
    "s_waitcnt vmcnt(0)"
    : "=&v"(v0), "=&v"(v1), "=&v"(v2), "=&v"(v3)
    : "v"(p)
    : "memory");
}
__device__ __forceinline__ void row_store_coh(float* p,
                                              f32x4 v0, f32x4 v1, f32x4 v2, f32x4 v3){
  asm volatile(
    "global_store_dwordx4 %0, %1, off sc0 sc1\n\t"
    "global_store_dwordx4 %0, %2, off offset:16 sc0 sc1\n\t"
    "global_store_dwordx4 %0, %3, off offset:32 sc0 sc1\n\t"
    "global_store_dwordx4 %0, %4, off offset:48 sc0 sc1"
    :: "v"(p), "v"(v0), "v"(v1), "v"(v2), "v"(v3)
    : "memory");
}

// ---------------- zero counters / indeg / cnum / fill / level counters ----------
__global__ void k_zero0(int* ints, int* lvl_cnt, int* indeg, int* cnum, int* fill, int N){
  int i = blockIdx.x*blockDim.x + threadIdx.x;
  int stride = gridDim.x*blockDim.x;
  if(i<1024) ints[i]=0;
  if(i<2048) lvl_cnt[i]=0;
  for(int j=i;j<N;j+=stride){ indeg[j]=0; cnum[j]=0; fill[j]=0; }
}

// ---------------- precompute h_init, t_init, gh_init, c0 ----------------
// consts (floats): [0..127]=h_init [128..255]=t_init [256..639]=gh(r,z,n) [640]=c0
__global__ void k_init(const float* emd_w, const float* emd_b,
                       const float* agg_w, const float* agg_b,
                       const float* w_hh, const float* b_hh,
                       const float* w1,const float* b1,const float* w2,const float* b2,
                       const float* w3,const float* b3,
                       float* consts){
  __shared__ float hl[128];
  __shared__ float z1[32];
  __shared__ float z2[32];
  int t = threadIdx.x;
  float h = emd_w[t] + emd_b[t];
  hl[t] = h; consts[t] = h;
  __syncthreads();
  float s = agg_b[t];
  for(int k=0;k<128;k++) s += agg_w[t*128+k]*hl[k];
  consts[128+t] = s;
  for(int g=t; g<G3; g+=128){
    float q = b_hh[g];
    for(int k=0;k<128;k++) q += w_hh[g*128+k]*hl[k];
    consts[256+g] = q;
  }
  if(t<32){
    float a = b1[t];
    for(int k=0;k<128;k++) a += w1[t*128+k]*hl[k];
    z1[t] = fmaxf(a,0.f);
  }
  __syncthreads();
  if(t<32){
    float a = b2[t];
    for(int k=0;k<32;k++) a += w2[t*32+k]*z1[k];
    z2[t] = fmaxf(a,0.f);
  }
  __syncthreads();
  if(t==0){
    float a = b3[0];
    for(int k=0;k<32;k++) a += w3[k]*z2[k];
    consts[640] = a;
  }
}

// ---------------- split weights into bf16 hi/lo ----------------
__global__ void k_wprep(const float* w_ih, const float* agg_w, const float* w1,
                        unsigned short* wih_h, unsigned short* wih_l,
                        unsigned short* agg_h, unsigned short* agg_l,
                        unsigned short* w1_h, unsigned short* w1_l){
  int i = blockIdx.x*blockDim.x + threadIdx.x;
  int stride = gridDim.x*blockDim.x;
  for(int idx=i; idx<G3*KP; idx+=stride){
    int g = idx/KP, k = idx - g*KP;
    float v = (k<DIN)? w_ih[g*DIN+k] : 0.f;
    unsigned short h = f2bf(v);
    wih_h[idx]=h; wih_l[idx]=f2bf(v-bf2f(h));
  }
  for(int idx=i; idx<DHID*DHID; idx+=stride){
    float v = agg_w[idx];
    unsigned short h=f2bf(v); agg_h[idx]=h; agg_l[idx]=f2bf(v-bf2f(h));
  }
  for(int idx=i; idx<32*DHID; idx+=stride){
    float v = w1[idx];
    unsigned short h=f2bf(v); w1_h[idx]=h; w1_l[idx]=f2bf(v-bf2f(h));
  }
}

// ---------------- node histogram by level ----------------
// ints: node_cnt@0(16) node_off@32(17) node_fill@64(16) tile_off@96(17)
__global__ void k_count(const int* fl, int N, int* ints){
  __shared__ int hn[16];
  int tid = threadIdx.x;
  if(tid<16) hn[tid]=0;
  __syncthreads();
  int i = blockIdx.x*blockDim.x+tid;
  int stride = gridDim.x*blockDim.x;
  for(int j=i;j<N;j+=stride) atomicAdd(&hn[fl[j]], 1);
  __syncthreads();
  if(tid<16 && hn[tid]) atomicAdd(&ints[tid], hn[tid]);
}

__global__ void k_prefix(int* ints){
  if(threadIdx.x==0 && blockIdx.x==0){
    int o=0;
    for(int l=0;l<NLEV;l++){ ints[32+l]=o; ints[64+l]=o; o+=ints[l]; }
    ints[32+NLEV]=o;
    int to=0;
    ints[96]=0;
    for(int l=1;l<NLEV;l++){ ints[96+l]=to; to += (ints[l]+TN-1)/TN; }
    ints[96+NLEV]=to;   // total tiles
  }
}

// Two-pass per-block counting sort of nodes by level.
__global__ void k_build(const int* fl, int N, int* ints,
                        int* node_list, int* node_rank){
  __shared__ int h[16], base[16];
  int tid = threadIdx.x;
  int nchunk = (N + gridDim.x - 1)/gridDim.x;
  int lo = blockIdx.x*nchunk;
  int hi = lo + nchunk; if(hi>N) hi=N;
  if(tid<16) h[tid]=0;
  __syncthreads();
  for(int j=lo+tid; j<hi; j+=blockDim.x) atomicAdd(&h[fl[j]],1);
  __syncthreads();
  if(tid<16){ base[tid] = h[tid] ? atomicAdd(&ints[64+tid], h[tid]) : 0; h[tid]=0; }
  __syncthreads();
  for(int j=lo+tid; j<hi; j+=blockDim.x){
    int lev = fl[j];
    int pos = base[lev] + atomicAdd(&h[lev],1);
    node_list[pos]=j;
    node_rank[j]=pos-ints[32+lev];
  }
}

// ------ indegree split: REAL edges (1<=fl[s]<fl[tg]) vs CONST edges (count only) --
__global__ void k_indeg(const int* ei, const int* fl, const int* node_rank,
                        const int* ints, int* indeg, int* cnum, int E){
  int i = blockIdx.x*blockDim.x+threadIdx.x;
  int stride = gridDim.x*blockDim.x;
  for(int e=i;e<E;e+=stride){
    int s  = ei[e];
    int tg = ei[E+e];
    int flt = fl[tg];
    int p = ints[32+flt] + node_rank[tg];
    int fls = fl[s];
    if(fls>=1 && fls<flt) atomicAdd(&indeg[p],1);
    else                  atomicAdd(&cnum[p],1);
  }
}

// ---------------- hierarchical exclusive scan of indeg -> row_ptr ----------------
__global__ void k_scan_a(const int* indeg, int* bsum, int N){
  __shared__ int ts[256];
  int b=blockIdx.x, t=threadIdx.x;
  int base=b*SCAN_CHUNK+t*8; int s=0;
  for(int j=0;j<8;j++){ int idx=base+j; if(idx<N) s+=indeg[idx]; }
  ts[t]=s; __syncthreads();
  for(int off=128;off>0;off>>=1){ if(t<off) ts[t]+=ts[t+off]; __syncthreads(); }
  if(t==0) bsum[b]=ts[0];
}
__global__ void k_scan_b(int* bsum, int nb){
  __shared__ int ls[256];
  int t=threadIdx.x;
  int v = (t<nb)? bsum[t]:0; ls[t]=v; __syncthreads();
  for(int off=1;off<256;off<<=1){
    int add = (t>=off)? ls[t-off]:0;
    __syncthreads();
    ls[t]+=add;
    __syncthreads();
  }
  if(t<nb) bsum[t] = ls[t]-v;   // exclusive
}
__global__ void k_scan_c(const int* indeg, const int* bsum, int* row_ptr, int N){
  __shared__ int ts[256];
  int b=blockIdx.x, t=threadIdx.x;
  int base=b*SCAN_CHUNK+t*8;
  int v[8]; int s=0;
  for(int j=0;j<8;j++){ int idx=base+j; v[j]=(idx<N)?indeg[idx]:0; s+=v[j]; }
  ts[t]=s; __syncthreads();
  for(int off=1;off<256;off<<=1){
    int add = (t>=off)? ts[t-off]:0;
    __syncthreads();
    ts[t]+=add;
    __syncthreads();
  }
  int excl = bsum[b] + ((t>0)? ts[t-1]:0);
  for(int j=0;j<8;j++){ int idx=base+j; if(idx<N) row_ptr[idx]=excl; excl+=v[j]; }
}

// ------- place ONLY real edges into CSR -------
__global__ void k_place(const int* ei, const int* fl, const int* node_rank,
                        const int* ints, const int* row_ptr, int* fill,
                        int* edge_src, int E){
  int i = blockIdx.x*blockDim.x+threadIdx.x;
  int stride = gridDim.x*blockDim.x;
  for(int e=i;e<E;e+=stride){
    int s  = ei[e];
    int tg = ei[E+e];
    int flt = fl[tg];
    int fls = fl[s];
    if(fls>=1 && fls<flt){
      int p = ints[32+flt] + node_rank[tg];
      int slot = atomicAdd(&fill[p],1);
      edge_src[row_ptr[p]+slot] = s;
    }
  }
}

// ---------------- out = c0 for LEVEL-0 nodes only (never updated later) ---------
__global__ void k_outc(const int* node_list, const int* ints,
                       float* out, const float* consts){
  int cnt0 = ints[0];
  float c0 = consts[640];
  int i = blockIdx.x*blockDim.x+threadIdx.x;
  int stride = gridDim.x*blockDim.x;
  for(int j=i;j<cnt0;j+=stride) out[node_list[j]]=c0;
}

// ================= persistent kernel, coherent tbuf + per-level counters =========
// 256 blocks x 512 threads, 1 block/CU guaranteed. GEMM weights in registers.
// tbuf accessed ONLY via sc0|sc1 ops. CSR holds only REAL edges (prefiltered);
// const contributions folded into cnum[p] * t_init. Low-register per-edge loads.
__global__ __launch_bounds__(BLK,2) void k_levels(
    const float* __restrict__ x, const int* __restrict__ node_list,
    const int* __restrict__ row_ptr, const int* __restrict__ indeg,
    const int* __restrict__ cnum, const int* __restrict__ edge_src,
    float* __restrict__ tbuf,
    const unsigned short* __restrict__ wih_h, const unsigned short* __restrict__ wih_l,
    const unsigned short* __restrict__ agg_h, const unsigned short* __restrict__ agg_l,
    const unsigned short* __restrict__ w1_h, const unsigned short* __restrict__ w1_l,
    const float* __restrict__ b_ih, const float* __restrict__ agg_b,
    const float* __restrict__ b1, const float* __restrict__ w2,
    const float* __restrict__ b2, const float* __restrict__ w3,
    const float* __restrict__ b3,
    const float* __restrict__ consts, float* __restrict__ out,
    int* ints, int* lvl_cnt)
{
  __shared__ __align__(16) unsigned char smem[64256];
  unsigned short* Ahi = (unsigned short*)smem;
  unsigned short* Alo = (unsigned short*)(smem + 21504);
  unsigned short* Hhi = (unsigned short*)smem;
  unsigned short* Hlo = (unsigned short*)(smem + 17408);
  float* tst = (float*)smem;                 // [64][132]
  float* z1l = (float*)(smem + 43008);
  float* z2l = (float*)(smem + 51456);
  float* w2t = (float*)(smem + 59904);
  float* w3l = (float*)(smem + 64128);

  int tid = threadIdx.x;
  int wv = tid>>6, ln = tid&63, lr = ln&15, lq = ln>>4;
  int cgo = tid&7, nd = tid>>3;    // gather: 8 thr/node, 16 dims each
  int d = wv*16 + lr;              // this lane's output dim (GEMM1/2)
  int mB = wv>>1, nB = wv&1;       // MLP1 sub-tile

  // ---- persistent weight fragments (w_ih + agg) ----
  short8_t wfh[15], wfl[15];
  #pragma unroll
  for(int g=0;g<3;g++)
    #pragma unroll
    for(int kk=0;kk<5;kk++){
      long long ro = (long long)(g*128 + d)*KP + kk*32 + lq*8;
      wfh[g*5+kk] = *(const short8_t*)&wih_h[ro];
      wfl[g*5+kk] = *(const short8_t*)&wih_l[ro];
    }
  short8_t agh[4], agl[4];
  #pragma unroll
  for(int kk=0;kk<4;kk++){
    int ro = d*DHID + kk*32 + lq*8;
    agh[kk] = *(const short8_t*)&agg_h[ro];
    agl[kk] = *(const short8_t*)&agg_l[ro];
  }
  float ghr=consts[256+d], ghz=consts[384+d], ghn=consts[512+d], h0c=consts[d];
  float bir=b_ih[d], biz=b_ih[128+d], bin_=b_ih[256+d], ab2=agg_b[d];
  float b1o = b1[nB*16+lr];
  f32x4 ti[4];
  { const f32x4* c4=(const f32x4*)(consts+128);
    #pragma unroll
    for(int q=0;q<4;q++) ti[q]=c4[cgo*4+q]; }

  // ---- stage small fp32 weights ----
  for(int idx=tid; idx<1024; idx+=BLK){ int j=idx>>5, k=idx&31;  w2t[k*33+j]=w2[idx]; }
  if(tid<32) w3l[tid]=w3[tid];
  __syncthreads();

  int total_tiles = ints[96+NLEV];
  int l = 1;

  for(int T = blockIdx.x; T < total_tiles; T += GRID){
    while(l < NLEV-1 && T >= ints[96+l+1]) l++;
    int cnt  = ints[l];
    int base = ints[32+l];
    int n0 = (T - ints[96+l])*TN;

    // ---- x into A cols 128..143, zero 144..159 (pre-wait; no tbuf access) ----
    if(tid<256){
      int i = tid>>2, j = tid&3;
      int gi = n0+i;
      float4 xv = make_float4(0.f,0.f,0.f,0.f);
      if(gi<cnt) xv = ((const float4*)x)[node_list[base+gi]*4 + j];
      float vv[4]={xv.x,xv.y,xv.z,xv.w};
      #pragma unroll
      for(int q=0;q<4;q++){
        unsigned short h=f2bf(vv[q]);
        Ahi[i*AS+128+j*4+q]=h;
        Alo[i*AS+128+j*4+q]=f2bf(vv[q]-bf2f(h));
      }
      #pragma unroll
      for(int q=0;q<4;q++){ Ahi[i*AS+144+j*4+q]=0; Alo[i*AS+144+j*4+q]=0; }
    }

    // ---- wait: previous level fully done (single counter, backoff poll) ----
    if(tid==0 && l>1){
      int need = ints[96+l] - ints[96+l-1];
      if(need>0){
        int it=0;
        while(__hip_atomic_load(&lvl_cnt[(l-1)*32], __ATOMIC_RELAXED,
                                __HIP_MEMORY_SCOPE_AGENT) < need){
          if(it<8) __builtin_amdgcn_s_sleep(8);
          else     __builtin_amdgcn_s_sleep(32);
          it++;
        }
      }
    }
    __syncthreads();

    // ---- phase 0: gather msg (real edges only) -> bf16 hi/lo into A ----
    {
      f32x4 a[4];
      int gi = n0+nd;
      if(gi<cnt){
        int p = base+gi;
        int r0 = row_ptr[p], dr = indeg[p];
        float fdc = (float)cnum[p];
        #pragma unroll
        for(int q=0;q<4;q++) a[q] = fdc*ti[q];
        for(int e=0;e<dr;e++){
          int s = edge_src[r0+e];
          const float* sp = tbuf + ((long long)s*128 + cgo*16);
          f32x4 v0,v1,v2,v3;
          row_load_coh(sp, v0,v1,v2,v3);
          a[0]+=v0; a[1]+=v1; a[2]+=v2; a[3]+=v3;
        }
      } else {
        #pragma unroll
        for(int q=0;q<4;q++) a[q]=(f32x4){0.f,0.f,0.f,0.f};
      }
      #pragma unroll
      for(int hf=0; hf<2; hf++){
        short8_t hv, lv;
        #pragma unroll
        for(int j=0;j<8;j++){
          float v = a[hf*2 + (j>>2)][j&3];
          unsigned short h = f2bf(v);
          hv[j]=(short)h; lv[j]=(short)f2bf(v-bf2f(h));
        }
        *(short8_t*)&Ahi[nd*AS + cgo*16 + hf*8] = hv;
        *(short8_t*)&Alo[nd*AS + cgo*16 + hf*8] = lv;
      }
    }
    __syncthreads();   // sync1: A ready

    // ---- prefetch w1 fragments (used in phase 3; hides under GEMM1) ----
    short8_t w1fh[4], w1fl[4];
    #pragma unroll
    for(int kk=0;kk<4;kk++){
      int ro = (nB*16+lr)*DHID + kk*32 + lq*8;
      w1fh[kk] = *(const short8_t*)&w1_h[ro];
      w1fl[kk] = *(const short8_t*)&w1_l[ro];
    }

    // ---- phase 1: GEMM1 (bf16x3 MFMA, weights in regs), 4 node-blocks ----
    f32x4 Ar[4],Az[4],An[4];
    #pragma unroll
    for(int m=0;m<4;m++){
      Ar[m]=(f32x4){bir,bir,bir,bir};
      Az[m]=(f32x4){biz,biz,biz,biz};
      An[m]=(f32x4){bin_,bin_,bin_,bin_};
    }
    #pragma unroll
    for(int kk=0;kk<5;kk++){
      short8_t ah[4], al[4];
      #pragma unroll
      for(int m=0;m<4;m++){
        int off = (m*16+lr)*AS + kk*32 + lq*8;
        ah[m]=*(const short8_t*)&Ahi[off];
        al[m]=*(const short8_t*)&Alo[off];
      }
      #pragma unroll
      for(int m=0;m<4;m++){
        Ar[m]=__builtin_amdgcn_mfma_f32_16x16x32_bf16(ah[m],wfh[kk],   Ar[m],0,0,0);
        Ar[m]=__builtin_amdgcn_mfma_f32_16x16x32_bf16(ah[m],wfl[kk],   Ar[m],0,0,0);
        Ar[m]=__builtin_amdgcn_mfma_f32_16x16x32_bf16(al[m],wfh[kk],   Ar[m],0,0,0);
        Az[m]=__builtin_amdgcn_mfma_f32_16x16x32_bf16(ah[m],wfh[5+kk], Az[m],0,0,0);
        Az[m]=__builtin_amdgcn_mfma_f32_16x16x32_bf16(ah[m],wfl[5+kk], Az[m],0,0,0);
        Az[m]=__builtin_amdgcn_mfma_f32_16x16x32_bf16(al[m],wfh[5+kk], Az[m],0,0,0);
        An[m]=__builtin_amdgcn_mfma_f32_16x16x32_bf16(ah[m],wfh[10+kk],An[m],0,0,0);
        An[m]=__builtin_amdgcn_mfma_f32_16x16x32_bf16(ah[m],wfl[10+kk],An[m],0,0,0);
        An[m]=__builtin_amdgcn_mfma_f32_16x16x32_bf16(al[m],wfh[10+kk],An[m],0,0,0);
      }
    }
    __syncthreads();   // sync2: all A reads done, H may overwrite

    // ---- phase 2: GRU gates -> H (bf16 hi/lo over A region) ----
    #pragma unroll
    for(int m=0;m<4;m++){
      #pragma unroll
      for(int j=0;j<4;j++){
        float r = sigmoidf_(Ar[m][j] + ghr);
        float z = sigmoidf_(Az[m][j] + ghz);
        float n = tanhf_(An[m][j] + r*ghn);
        float h = (1.f-z)*n + z*h0c;
        int node = m*16 + lq*4 + j;
        unsigned short hb = f2bf(h);
        Hhi[node*HS + d] = hb;
        Hlo[node*HS + d] = f2bf(h - bf2f(hb));
      }
    }
    __syncthreads();   // sync3: H ready

    // ---- phase 3: GEMM2 (t, all waves) + MLP1 (z1, MFMA per-wave sub-tile) ----
    f32x4 T2[4];
    #pragma unroll
    for(int m=0;m<4;m++) T2[m]=(f32x4){ab2,ab2,ab2,ab2};
    f32x4 M1 = (f32x4){b1o,b1o,b1o,b1o};
    #pragma unroll
    for(int kk=0;kk<4;kk++){
      short8_t hh[4], hl2[4];
      #pragma unroll
      for(int m=0;m<4;m++){
        int off = (m*16+lr)*HS + kk*32 + lq*8;
        hh[m]=*(const short8_t*)&Hhi[off];
        hl2[m]=*(const short8_t*)&Hlo[off];
      }
      #pragma unroll
      for(int m=0;m<4;m++){
        T2[m]=__builtin_amdgcn_mfma_f32_16x16x32_bf16(hh[m], agh[kk],T2[m],0,0,0);
        T2[m]=__builtin_amdgcn_mfma_f32_16x16x32_bf16(hh[m], agl[kk],T2[m],0,0,0);
        T2[m]=__builtin_amdgcn_mfma_f32_16x16x32_bf16(hl2[m],agh[kk],T2[m],0,0,0);
      }
      M1=__builtin_amdgcn_mfma_f32_16x16x32_bf16(hh[mB], w1fh[kk],M1,0,0,0);
      M1=__builtin_amdgcn_mfma_f32_16x16x32_bf16(hh[mB], w1fl[kk],M1,0,0,0);
      M1=__builtin_amdgcn_mfma_f32_16x16x32_bf16(hl2[mB],w1fh[kk],M1,0,0,0);
    }
    #pragma unroll
    for(int j=0;j<4;j++){
      int node = mB*16 + lq*4 + j;
      z1l[node*33 + nB*16+lr] = fmaxf(M1[j],0.f);
    }
    __syncthreads();   // sync4: H reads done; tst may overwrite; z1 ready

    // ---- phase 4: stage t into LDS (fp32) + MLP2 (VALU) ----
    #pragma unroll
    for(int m=0;m<4;m++){
      #pragma unroll
      for(int j=0;j<4;j++){
        int node = m*16 + lq*4 + j;
        tst[node*132 + d] = T2[m][j];
      }
    }
    {
      int ndl = tid>>3, jo = (tid&7)*4;
      float s0=b2[jo], s1=b2[jo+1], s2=b2[jo+2], s3=b2[jo+3];
      #pragma unroll 8
      for(int k=0;k<32;k++){
        float zv = z1l[ndl*33+k];
        s0 += zv*w2t[k*33+jo];
        s1 += zv*w2t[k*33+jo+1];
        s2 += zv*w2t[k*33+jo+2];
        s3 += zv*w2t[k*33+jo+3];
      }
      z2l[ndl*33+jo]   = fmaxf(s0,0.f);
      z2l[ndl*33+jo+1] = fmaxf(s1,0.f);
      z2l[ndl*33+jo+2] = fmaxf(s2,0.f);
      z2l[ndl*33+jo+3] = fmaxf(s3,0.f);
    }
    __syncthreads();   // sync5: tst + z2 ready

    // ---- phase 5: coherent t store + out store ----
    {
      int nd2 = tid>>3, q = tid&7;
      int gi = n0+nd2;
      if(gi<cnt){
        long long v = node_list[base+gi];
        float* dp = tbuf + v*128 + q*16;
        f32x4 v0 = *(const f32x4*)&tst[nd2*132 + q*16];
        f32x4 v1 = *(const f32x4*)&tst[nd2*132 + q*16 + 4];
        f32x4 v2 = *(const f32x4*)&tst[nd2*132 + q*16 + 8];
        f32x4 v3 = *(const f32x4*)&tst[nd2*132 + q*16 + 12];
        row_store_coh(dp, v0,v1,v2,v3);
      }
    }
    if(tid<TN){
      int gi = n0+tid;
      if(gi<cnt){
        float s = b3[0];
        #pragma unroll 8
        for(int k=0;k<32;k++) s += z2l[tid*33+k]*w3l[k];
        out[node_list[base+gi]] = s;
      }
    }
    __syncthreads();   // sync6: every wave drains vmcnt -> stores device-visible

    // ---- publish: one RELAXED add on this level's counter ----
    if(tid==0){
      asm volatile("s_waitcnt vmcnt(0)" ::: "memory");
      __hip_atomic_fetch_add(&lvl_cnt[l*32], 1, __ATOMIC_RELAXED,
                             __HIP_MEMORY_SCOPE_AGENT);
    }
  }
}

extern "C" void kernel_launch(void* const* d_in, const int* in_sizes, int n_in,
                              void* d_out, int out_size, void* d_ws, size_t ws_size,
                              hipStream_t stream){
  const float* x     = (const float*)d_in[0];
  const int*   ei    = (const int*)  d_in[1];
  const int*   fl    = (const int*)  d_in[2];
  const float* emd_w = (const float*)d_in[4];
  const float* emd_b = (const float*)d_in[5];
  const float* agg_w = (const float*)d_in[6];
  const float* agg_b = (const float*)d_in[7];
  const float* w_ih  = (const float*)d_in[8];
  const float* w_hh  = (const float*)d_in[9];
  const float* b_ih  = (const float*)d_in[10];
  const float* b_hh  = (const float*)d_in[11];
  const float* w1    = (const float*)d_in[12];
  const float* b1    = (const float*)d_in[13];
  const float* w2    = (const float*)d_in[14];
  const float* b2    = (const float*)d_in[15];
  const float* w3    = (const float*)d_in[16];
  const float* b3    = (const float*)d_in[17];
  float* out = (float*)d_out;

  int N = in_sizes[2];
  int E = in_sizes[1]/2;
  int nb = (N + SCAN_CHUNK - 1)/SCAN_CHUNK;

  char* ws = (char*)d_ws;
  float* consts   = (float*)ws;                    // 4 KiB
  int*   ints     = (int*)(ws + 4096);             // 4 KiB (tile_off@96)
  int*   node_list= (int*)(ws + 8192);
  int*   node_rank= node_list + N;
  int*   indeg    = node_rank + N;                 // REAL indegree
  int*   cnum     = indeg + N;                     // const-edge count
  int*   row_ptr  = cnum + N;
  int*   fill     = row_ptr + N;
  int*   bsum     = fill + N;                      // 1024 block sums
  int*   lvl_cnt  = bsum + 1024;                   // 2048
  int*   edge_src = lvl_cnt + 2048;                // <= E ints (real edges only)
  size_t off0 = 8192 + ((size_t)6*N + 1024 + 2048 + (size_t)E)*4;
  off0 = (off0 + 255) & ~(size_t)255;
  unsigned short* wih_h = (unsigned short*)(ws + off0);       // 384*160
  unsigned short* wih_l = wih_h + G3*KP;
  unsigned short* agg_h = wih_l + G3*KP;                      // 128*128
  unsigned short* agg_l = agg_h + DHID*DHID;
  unsigned short* w1_h  = agg_l + DHID*DHID;                  // 32*128
  unsigned short* w1_l  = w1_h + 32*DHID;
  size_t off1 = off0 + (size_t)(2*G3*KP + 2*DHID*DHID + 2*32*DHID)*2;
  off1 = (off1 + 255) & ~(size_t)255;
  float* tbuf = (float*)(ws + off1);               // N*128 floats, never pre-initialized
  size_t need = off1 + (size_t)N*128*4;
  if(ws_size < need) return;

  k_zero0  <<<512,256,0,stream>>>(ints, lvl_cnt, indeg, cnum, fill, N);
  k_init   <<<1,128,0,stream>>>(emd_w,emd_b,agg_w,agg_b,w_hh,b_hh,w1,b1,w2,b2,w3,b3,consts);
  k_wprep  <<<256,256,0,stream>>>(w_ih,agg_w,w1,wih_h,wih_l,agg_h,agg_l,w1_h,w1_l);
  k_count  <<<512,256,0,stream>>>(fl,N,ints);
  k_prefix <<<1,1,0,stream>>>(ints);
  k_build  <<<512,256,0,stream>>>(fl,N,ints,node_list,node_rank);
  k_indeg  <<<1024,256,0,stream>>>(ei,fl,node_rank,ints,indeg,cnum,E);
  k_scan_a <<<nb,256,0,stream>>>(indeg,bsum,N);
  k_scan_b <<<1,256,0,stream>>>(bsum,nb);
  k_scan_c <<<nb,256,0,stream>>>(indeg,bsum,row_ptr,N);
  k_place  <<<1024,256,0,stream>>>(ei,fl,node_rank,ints,row_ptr,fill,edge_src,E);
  k_outc   <<<256,256,0,stream>>>(node_list,ints,out,consts);
  k_levels <<<GRID,BLK,0,stream>>>(x,node_list,row_ptr,indeg,cnum,edge_src,tbuf,
                                   wih_h,wih_l,agg_h,agg_l,w1_h,w1_l,
                                   b_ih,agg_b,b1,w2,b2,w3,b3,
                                   consts,out,ints,lvl_cnt);
}

// Round 13
// 941.820 us; speedup vs baseline: 1.2621x; 1.0760x over previous
//
#include <hip/hip_runtime.h>
#include <math.h>

// Problem dims (fixed by the reference file)
#define DHID 128
#define DXIN 16
#define DIN  144   // DHID + DXIN
#define G3   384   // 3*DHID
#define NLEV 16
#define SCAN_CHUNK 2048
#define KP   160   // GEMM1 K padded to mult of 32
#define AS   168   // A LDS row stride in bf16 units
#define HS   136   // H LDS row stride in bf16 units
#define TN   64    // tile nodes
#define GRID 256
#define BLK  512

typedef __attribute__((ext_vector_type(8))) short short8_t;
typedef __attribute__((ext_vector_type(4))) float f32x4;

__device__ __forceinline__ float sigmoidf_(float v){ return 1.0f/(1.0f + __expf(-v)); }
__device__ __forceinline__ float tanhf_(float v){
  v = fminf(fmaxf(v,-15.f),15.f);
  float e = __expf(2.f*v);
  return (e-1.f)/(e+1.f);
}
__device__ __forceinline__ unsigned short f2bf(float f){
  unsigned u = __float_as_uint(f);
  u = u + 0x7FFFu + ((u>>16)&1u);
  return (unsigned short)(u>>16);
}
__device__ __forceinline__ float bf2f(unsigned short h){
  return __uint_as_float(((unsigned)h)<<16);
}

// coherent (device-scope, L2-bypass) 64B row-quarter load (r9-proven, low-reg)
__device__ __forceinline__ void row_load_coh(const float* p,
                                             f32x4& v0, f32x4& v1, f32x4& v2, f32x4& v3){
  asm volatile(
    "global_load_dwordx4 %0, %4, off sc0 sc1\n\t"
    "global_load_dwordx4 %1, %4, off offset:16 sc0 sc1\n\t"
    "global_load_dwordx4 %2, %4, off offset:32 sc0 sc1\n\t"
    "global_load_dwordx4 %3, %4, off offset:48 sc0 sc1\n\t"
    "s_waitcnt vmcnt(0)"
    : "=&v"(v0), "=&v"(v1), "=&v"(v2), "=&v"(v3)
    : "v"(p)
    : "memory");
}
__device__ __forceinline__ void row_store_coh(float* p,
                                              f32x4 v0, f32x4 v1, f32x4 v2, f32x4 v3){
  asm volatile(
    "global_store_dwordx4 %0, %1, off sc0 sc1\n\t"
    "global_store_dwordx4 %0, %2, off offset:16 sc0 sc1\n\t"
    "global_store_dwordx4 %0, %3, off offset:32 sc0 sc1\n\t"
    "global_store_dwordx4 %0, %4, off offset:48 sc0 sc1"
    :: "v"(p), "v"(v0), "v"(v1), "v"(v2), "v"(v3)
    : "memory");
}

// ---------------- zero counters / indeg / cnum / fill / level counters ----------
__global__ void k_zero0(int* ints, int* lvl_cnt, int* indeg, int* cnum, int* fill, int N){
  int i = blockIdx.x*blockDim.x + threadIdx.x;
  int stride = gridDim.x*blockDim.x;
  if(i<1024) ints[i]=0;
  if(i<2048) lvl_cnt[i]=0;
  for(int j=i;j<N;j+=stride){ indeg[j]=0; cnum[j]=0; fill[j]=0; }
}

// ---------------- precompute h_init, t_init, gh_init, c0 ----------------
// consts (floats): [0..127]=h_init [128..255]=t_init [256..639]=gh(r,z,n) [640]=c0
__global__ void k_init(const float* emd_w, const float* emd_b,
                       const float* agg_w, const float* agg_b,
                       const float* w_hh, const float* b_hh,
                       const float* w1,const float* b1,const float* w2,const float* b2,
                       const float* w3,const float* b3,
                       float* consts){
  __shared__ float hl[128];
  __shared__ float z1[32];
  __shared__ float z2[32];
  int t = threadIdx.x;
  float h = emd_w[t] + emd_b[t];
  hl[t] = h; consts[t] = h;
  __syncthreads();
  float s = agg_b[t];
  for(int k=0;k<128;k++) s += agg_w[t*128+k]*hl[k];
  consts[128+t] = s;
  for(int g=t; g<G3; g+=128){
    float q = b_hh[g];
    for(int k=0;k<128;k++) q += w_hh[g*128+k]*hl[k];
    consts[256+g] = q;
  }
  if(t<32){
    float a = b1[t];
    for(int k=0;k<128;k++) a += w1[t*128+k]*hl[k];
    z1[t] = fmaxf(a,0.f);
  }
  __syncthreads();
  if(t<32){
    float a = b2[t];
    for(int k=0;k<32;k++) a += w2[t*32+k]*z1[k];
    z2[t] = fmaxf(a,0.f);
  }
  __syncthreads();
  if(t==0){
    float a = b3[0];
    for(int k=0;k<32;k++) a += w3[k]*z2[k];
    consts[640] = a;
  }
}

// ---------------- split weights into bf16 hi/lo ----------------
__global__ void k_wprep(const float* w_ih, const float* agg_w, const float* w1,
                        unsigned short* wih_h, unsigned short* wih_l,
                        unsigned short* agg_h, unsigned short* agg_l,
                        unsigned short* w1_h, unsigned short* w1_l){
  int i = blockIdx.x*blockDim.x + threadIdx.x;
  int stride = gridDim.x*blockDim.x;
  for(int idx=i; idx<G3*KP; idx+=stride){
    int g = idx/KP, k = idx - g*KP;
    float v = (k<DIN)? w_ih[g*DIN+k] : 0.f;
    unsigned short h = f2bf(v);
    wih_h[idx]=h; wih_l[idx]=f2bf(v-bf2f(h));
  }
  for(int idx=i; idx<DHID*DHID; idx+=stride){
    float v = agg_w[idx];
    unsigned short h=f2bf(v); agg_h[idx]=h; agg_l[idx]=f2bf(v-bf2f(h));
  }
  for(int idx=i; idx<32*DHID; idx+=stride){
    float v = w1[idx];
    unsigned short h=f2bf(v); w1_h[idx]=h; w1_l[idx]=f2bf(v-bf2f(h));
  }
}

// ---------------- node histogram by level ----------------
// ints: node_cnt@0(16) node_off@32(17) node_fill@64(16) tile_off@96(17)
__global__ void k_count(const int* fl, int N, int* ints){
  __shared__ int hn[16];
  int tid = threadIdx.x;
  if(tid<16) hn[tid]=0;
  __syncthreads();
  int i = blockIdx.x*blockDim.x+tid;
  int stride = gridDim.x*blockDim.x;
  for(int j=i;j<N;j+=stride) atomicAdd(&hn[fl[j]], 1);
  __syncthreads();
  if(tid<16 && hn[tid]) atomicAdd(&ints[tid], hn[tid]);
}

__global__ void k_prefix(int* ints){
  if(threadIdx.x==0 && blockIdx.x==0){
    int o=0;
    for(int l=0;l<NLEV;l++){ ints[32+l]=o; ints[64+l]=o; o+=ints[l]; }
    ints[32+NLEV]=o;
    int to=0;
    ints[96]=0;
    for(int l=1;l<NLEV;l++){ ints[96+l]=to; to += (ints[l]+TN-1)/TN; }
    ints[96+NLEV]=to;   // total tiles
  }
}

// Two-pass per-block counting sort of nodes by level.
__global__ void k_build(const int* fl, int N, int* ints,
                        int* node_list, int* node_rank){
  __shared__ int h[16], base[16];
  int tid = threadIdx.x;
  int nchunk = (N + gridDim.x - 1)/gridDim.x;
  int lo = blockIdx.x*nchunk;
  int hi = lo + nchunk; if(hi>N) hi=N;
  if(tid<16) h[tid]=0;
  __syncthreads();
  for(int j=lo+tid; j<hi; j+=blockDim.x) atomicAdd(&h[fl[j]],1);
  __syncthreads();
  if(tid<16){ base[tid] = h[tid] ? atomicAdd(&ints[64+tid], h[tid]) : 0; h[tid]=0; }
  __syncthreads();
  for(int j=lo+tid; j<hi; j+=blockDim.x){
    int lev = fl[j];
    int pos = base[lev] + atomicAdd(&h[lev],1);
    node_list[pos]=j;
    node_rank[j]=pos-ints[32+lev];
  }
}

// ------ indegree split: REAL edges (1<=fl[s]<fl[tg]) vs CONST edges (count only) --
__global__ void k_indeg(const int* ei, const int* fl, const int* node_rank,
                        const int* ints, int* indeg, int* cnum, int E){
  int i = blockIdx.x*blockDim.x+threadIdx.x;
  int stride = gridDim.x*blockDim.x;
  for(int e=i;e<E;e+=stride){
    int s  = ei[e];
    int tg = ei[E+e];
    int flt = fl[tg];
    int p = ints[32+flt] + node_rank[tg];
    int fls = fl[s];
    if(fls>=1 && fls<flt) atomicAdd(&indeg[p],1);
    else                  atomicAdd(&cnum[p],1);
  }
}

// ---------------- hierarchical exclusive scan of indeg -> row_ptr ----------------
__global__ void k_scan_a(const int* indeg, int* bsum, int N){
  __shared__ int ts[256];
  int b=blockIdx.x, t=threadIdx.x;
  int base=b*SCAN_CHUNK+t*8; int s=0;
  for(int j=0;j<8;j++){ int idx=base+j; if(idx<N) s+=indeg[idx]; }
  ts[t]=s; __syncthreads();
  for(int off=128;off>0;off>>=1){ if(t<off) ts[t]+=ts[t+off]; __syncthreads(); }
  if(t==0) bsum[b]=ts[0];
}
__global__ void k_scan_b(int* bsum, int nb){
  __shared__ int ls[256];
  int t=threadIdx.x;
  int v = (t<nb)? bsum[t]:0; ls[t]=v; __syncthreads();
  for(int off=1;off<256;off<<=1){
    int add = (t>=off)? ls[t-off]:0;
    __syncthreads();
    ls[t]+=add;
    __syncthreads();
  }
  if(t<nb) bsum[t] = ls[t]-v;   // exclusive
}
__global__ void k_scan_c(const int* indeg, const int* bsum, int* row_ptr, int N){
  __shared__ int ts[256];
  int b=blockIdx.x, t=threadIdx.x;
  int base=b*SCAN_CHUNK+t*8;
  int v[8]; int s=0;
  for(int j=0;j<8;j++){ int idx=base+j; v[j]=(idx<N)?indeg[idx]:0; s+=v[j]; }
  ts[t]=s; __syncthreads();
  for(int off=1;off<256;off<<=1){
    int add = (t>=off)? ts[t-off]:0;
    __syncthreads();
    ts[t]+=add;
    __syncthreads();
  }
  int excl = bsum[b] + ((t>0)? ts[t-1]:0);
  for(int j=0;j<8;j++){ int idx=base+j; if(idx<N) row_ptr[idx]=excl; excl+=v[j]; }
}

// ------- place ONLY real edges into CSR -------
__global__ void k_place(const int* ei, const int* fl, const int* node_rank,
                        const int* ints, const int* row_ptr, int* fill,
                        int* edge_src, int E){
  int i = blockIdx.x*blockDim.x+threadIdx.x;
  int stride = gridDim.x*blockDim.x;
  for(int e=i;e<E;e+=stride){
    int s  = ei[e];
    int tg = ei[E+e];
    int flt = fl[tg];
    int fls = fl[s];
    if(fls>=1 && fls<flt){
      int p = ints[32+flt] + node_rank[tg];
      int slot = atomicAdd(&fill[p],1);
      edge_src[row_ptr[p]+slot] = s;
    }
  }
}

// ---------------- out = c0 for LEVEL-0 nodes only (never updated later) ---------
__global__ void k_outc(const int* node_list, const int* ints,
                       float* out, const float* consts){
  int cnt0 = ints[0];
  float c0 = consts[640];
  int i = blockIdx.x*blockDim.x+threadIdx.x;
  int stride = gridDim.x*blockDim.x;
  for(int j=i;j<cnt0;j+=stride) out[node_list[j]]=c0;
}

// ================= persistent kernel, coherent tbuf + per-level counters =========
// 256 blocks x 512 threads, exactly 1 block/CU (grid == #CUs). GEMM weights live
// in VGPRs — launch_bounds(BLK,1) gives the 256-VGPR budget they need (the old
// (BLK,2) cap of 128 spilled ~170 regs to scratch = ~700 MB/launch of HBM spill
// traffic, for zero occupancy gain since grid already pins 1 block/CU).
__global__ __launch_bounds__(BLK,1) void k_levels(
    const float* __restrict__ x, const int* __restrict__ node_list,
    const int* __restrict__ row_ptr, const int* __restrict__ indeg,
    const int* __restrict__ cnum, const int* __restrict__ edge_src,
    float* __restrict__ tbuf,
    const unsigned short* __restrict__ wih_h, const unsigned short* __restrict__ wih_l,
    const unsigned short* __restrict__ agg_h, const unsigned short* __restrict__ agg_l,
    const unsigned short* __restrict__ w1_h, const unsigned short* __restrict__ w1_l,
    const float* __restrict__ b_ih, const float* __restrict__ agg_b,
    const float* __restrict__ b1, const float* __restrict__ w2,
    const float* __restrict__ b2, const float* __restrict__ w3,
    const float* __restrict__ b3,
    const float* __restrict__ consts, float* __restrict__ out,
    int* ints, int* lvl_cnt)
{
  __shared__ __align__(16) unsigned char smem[64256];
  unsigned short* Ahi = (unsigned short*)smem;
  unsigned short* Alo = (unsigned short*)(smem + 21504);
  unsigned short* Hhi = (unsigned short*)smem;
  unsigned short* Hlo = (unsigned short*)(smem + 17408);
  float* tst = (float*)smem;                 // [64][132]
  float* z1l = (float*)(smem + 43008);
  float* z2l = (float*)(smem + 51456);
  float* w2t = (float*)(smem + 59904);
  float* w3l = (float*)(smem + 64128);

  int tid = threadIdx.x;
  int wv = tid>>6, ln = tid&63, lr = ln&15, lq = ln>>4;
  int cgo = tid&7, nd = tid>>3;    // gather: 8 thr/node, 16 dims each
  int d = wv*16 + lr;              // this lane's output dim (GEMM1/2)
  int mB = wv>>1, nB = wv&1;       // MLP1 sub-tile

  // ---- persistent weight fragments (w_ih + agg) ----
  short8_t wfh[15], wfl[15];
  #pragma unroll
  for(int g=0;g<3;g++)
    #pragma unroll
    for(int kk=0;kk<5;kk++){
      long long ro = (long long)(g*128 + d)*KP + kk*32 + lq*8;
      wfh[g*5+kk] = *(const short8_t*)&wih_h[ro];
      wfl[g*5+kk] = *(const short8_t*)&wih_l[ro];
    }
  short8_t agh[4], agl[4];
  #pragma unroll
  for(int kk=0;kk<4;kk++){
    int ro = d*DHID + kk*32 + lq*8;
    agh[kk] = *(const short8_t*)&agg_h[ro];
    agl[kk] = *(const short8_t*)&agg_l[ro];
  }
  float ghr=consts[256+d], ghz=consts[384+d], ghn=consts[512+d], h0c=consts[d];
  float bir=b_ih[d], biz=b_ih[128+d], bin_=b_ih[256+d], ab2=agg_b[d];
  float b1o = b1[nB*16+lr];
  f32x4 ti[4];
  { const f32x4* c4=(const f32x4*)(consts+128);
    #pragma unroll
    for(int q=0;q<4;q++) ti[q]=c4[cgo*4+q]; }

  // ---- stage small fp32 weights ----
  for(int idx=tid; idx<1024; idx+=BLK){ int j=idx>>5, k=idx&31;  w2t[k*33+j]=w2[idx]; }
  if(tid<32) w3l[tid]=w3[tid];
  __syncthreads();

  int total_tiles = ints[96+NLEV];
  int l = 1;

  for(int T = blockIdx.x; T < total_tiles; T += GRID){
    while(l < NLEV-1 && T >= ints[96+l+1]) l++;
    int cnt  = ints[l];
    int base = ints[32+l];
    int n0 = (T - ints[96+l])*TN;

    // ---- x into A cols 128..143, zero 144..159 (pre-wait; no tbuf access) ----
    if(tid<256){
      int i = tid>>2, j = tid&3;
      int gi = n0+i;
      float4 xv = make_float4(0.f,0.f,0.f,0.f);
      if(gi<cnt) xv = ((const float4*)x)[node_list[base+gi]*4 + j];
      float vv[4]={xv.x,xv.y,xv.z,xv.w};
      #pragma unroll
      for(int q=0;q<4;q++){
        unsigned short h=f2bf(vv[q]);
        Ahi[i*AS+128+j*4+q]=h;
        Alo[i*AS+128+j*4+q]=f2bf(vv[q]-bf2f(h));
      }
      #pragma unroll
      for(int q=0;q<4;q++){ Ahi[i*AS+144+j*4+q]=0; Alo[i*AS+144+j*4+q]=0; }
    }

    // ---- wait: previous level fully done (single counter, backoff poll) ----
    if(tid==0 && l>1){
      int need = ints[96+l] - ints[96+l-1];
      if(need>0){
        int it=0;
        while(__hip_atomic_load(&lvl_cnt[(l-1)*32], __ATOMIC_RELAXED,
                                __HIP_MEMORY_SCOPE_AGENT) < need){
          if(it<8) __builtin_amdgcn_s_sleep(8);
          else     __builtin_amdgcn_s_sleep(32);
          it++;
        }
      }
    }
    __syncthreads();

    // ---- phase 0: gather msg (real edges only) -> bf16 hi/lo into A ----
    {
      f32x4 a[4];
      int gi = n0+nd;
      if(gi<cnt){
        int p = base+gi;
        int r0 = row_ptr[p], dr = indeg[p];
        float fdc = (float)cnum[p];
        #pragma unroll
        for(int q=0;q<4;q++) a[q] = fdc*ti[q];
        for(int e=0;e<dr;e++){
          int s = edge_src[r0+e];
          const float* sp = tbuf + ((long long)s*128 + cgo*16);
          f32x4 v0,v1,v2,v3;
          row_load_coh(sp, v0,v1,v2,v3);
          a[0]+=v0; a[1]+=v1; a[2]+=v2; a[3]+=v3;
        }
      } else {
        #pragma unroll
        for(int q=0;q<4;q++) a[q]=(f32x4){0.f,0.f,0.f,0.f};
      }
      #pragma unroll
      for(int hf=0; hf<2; hf++){
        short8_t hv, lv;
        #pragma unroll
        for(int j=0;j<8;j++){
          float v = a[hf*2 + (j>>2)][j&3];
          unsigned short h = f2bf(v);
          hv[j]=(short)h; lv[j]=(short)f2bf(v-bf2f(h));
        }
        *(short8_t*)&Ahi[nd*AS + cgo*16 + hf*8] = hv;
        *(short8_t*)&Alo[nd*AS + cgo*16 + hf*8] = lv;
      }
    }
    __syncthreads();   // sync1: A ready

    // ---- phase 1: GEMM1 (bf16x3 MFMA, weights in regs), 4 node-blocks ----
    f32x4 Ar[4],Az[4],An[4];
    #pragma unroll
    for(int m=0;m<4;m++){
      Ar[m]=(f32x4){bir,bir,bir,bir};
      Az[m]=(f32x4){biz,biz,biz,biz};
      An[m]=(f32x4){bin_,bin_,bin_,bin_};
    }
    #pragma unroll
    for(int kk=0;kk<5;kk++){
      short8_t ah[4], al[4];
      #pragma unroll
      for(int m=0;m<4;m++){
        int off = (m*16+lr)*AS + kk*32 + lq*8;
        ah[m]=*(const short8_t*)&Ahi[off];
        al[m]=*(const short8_t*)&Alo[off];
      }
      #pragma unroll
      for(int m=0;m<4;m++){
        Ar[m]=__builtin_amdgcn_mfma_f32_16x16x32_bf16(ah[m],wfh[kk],   Ar[m],0,0,0);
        Ar[m]=__builtin_amdgcn_mfma_f32_16x16x32_bf16(ah[m],wfl[kk],   Ar[m],0,0,0);
        Ar[m]=__builtin_amdgcn_mfma_f32_16x16x32_bf16(al[m],wfh[kk],   Ar[m],0,0,0);
        Az[m]=__builtin_amdgcn_mfma_f32_16x16x32_bf16(ah[m],wfh[5+kk], Az[m],0,0,0);
        Az[m]=__builtin_amdgcn_mfma_f32_16x16x32_bf16(ah[m],wfl[5+kk], Az[m],0,0,0);
        Az[m]=__builtin_amdgcn_mfma_f32_16x16x32_bf16(al[m],wfh[5+kk], Az[m],0,0,0);
        An[m]=__builtin_amdgcn_mfma_f32_16x16x32_bf16(ah[m],wfh[10+kk],An[m],0,0,0);
        An[m]=__builtin_amdgcn_mfma_f32_16x16x32_bf16(ah[m],wfl[10+kk],An[m],0,0,0);
        An[m]=__builtin_amdgcn_mfma_f32_16x16x32_bf16(al[m],wfh[10+kk],An[m],0,0,0);
      }
    }
    __syncthreads();   // sync2: all A reads done, H may overwrite

    // ---- prefetch w1 fragments here (after GEMM1 peak pressure; used phase 3) ----
    short8_t w1fh[4], w1fl[4];
    #pragma unroll
    for(int kk=0;kk<4;kk++){
      int ro = (nB*16+lr)*DHID + kk*32 + lq*8;
      w1fh[kk] = *(const short8_t*)&w1_h[ro];
      w1fl[kk] = *(const short8_t*)&w1_l[ro];
    }

    // ---- phase 2: GRU gates -> H (bf16 hi/lo over A region) ----
    #pragma unroll
    for(int m=0;m<4;m++){
      #pragma unroll
      for(int j=0;j<4;j++){
        float r = sigmoidf_(Ar[m][j] + ghr);
        float z = sigmoidf_(Az[m][j] + ghz);
        float n = tanhf_(An[m][j] + r*ghn);
        float h = (1.f-z)*n + z*h0c;
        int node = m*16 + lq*4 + j;
        unsigned short hb = f2bf(h);
        Hhi[node*HS + d] = hb;
        Hlo[node*HS + d] = f2bf(h - bf2f(hb));
      }
    }
    __syncthreads();   // sync3: H ready

    // ---- phase 3: GEMM2 (t, all waves) + MLP1 (z1, MFMA per-wave sub-tile) ----
    f32x4 T2[4];
    #pragma unroll
    for(int m=0;m<4;m++) T2[m]=(f32x4){ab2,ab2,ab2,ab2};
    f32x4 M1 = (f32x4){b1o,b1o,b1o,b1o};
    #pragma unroll
    for(int kk=0;kk<4;kk++){
      short8_t hh[4], hl2[4];
      #pragma unroll
      for(int m=0;m<4;m++){
        int off = (m*16+lr)*HS + kk*32 + lq*8;
        hh[m]=*(const short8_t*)&Hhi[off];
        hl2[m]=*(const short8_t*)&Hlo[off];
      }
      #pragma unroll
      for(int m=0;m<4;m++){
        T2[m]=__builtin_amdgcn_mfma_f32_16x16x32_bf16(hh[m], agh[kk],T2[m],0,0,0);
        T2[m]=__builtin_amdgcn_mfma_f32_16x16x32_bf16(hh[m], agl[kk],T2[m],0,0,0);
        T2[m]=__builtin_amdgcn_mfma_f32_16x16x32_bf16(hl2[m],agh[kk],T2[m],0,0,0);
      }
      M1=__builtin_amdgcn_mfma_f32_16x16x32_bf16(hh[mB], w1fh[kk],M1,0,0,0);
      M1=__builtin_amdgcn_mfma_f32_16x16x32_bf16(hh[mB], w1fl[kk],M1,0,0,0);
      M1=__builtin_amdgcn_mfma_f32_16x16x32_bf16(hl2[mB],w1fh[kk],M1,0,0,0);
    }
    #pragma unroll
    for(int j=0;j<4;j++){
      int node = mB*16 + lq*4 + j;
      z1l[node*33 + nB*16+lr] = fmaxf(M1[j],0.f);
    }
    __syncthreads();   // sync4: H reads done; tst may overwrite; z1 ready

    // ---- phase 4: stage t into LDS (fp32) + MLP2 (VALU) ----
    #pragma unroll
    for(int m=0;m<4;m++){
      #pragma unroll
      for(int j=0;j<4;j++){
        int node = m*16 + lq*4 + j;
        tst[node*132 + d] = T2[m][j];
      }
    }
    {
      int ndl = tid>>3, jo = (tid&7)*4;
      float s0=b2[jo], s1=b2[jo+1], s2=b2[jo+2], s3=b2[jo+3];
      #pragma unroll 8
      for(int k=0;k<32;k++){
        float zv = z1l[ndl*33+k];
        s0 += zv*w2t[k*33+jo];
        s1 += zv*w2t[k*33+jo+1];
        s2 += zv*w2t[k*33+jo+2];
        s3 += zv*w2t[k*33+jo+3];
      }
      z2l[ndl*33+jo]   = fmaxf(s0,0.f);
      z2l[ndl*33+jo+1] = fmaxf(s1,0.f);
      z2l[ndl*33+jo+2] = fmaxf(s2,0.f);
      z2l[ndl*33+jo+3] = fmaxf(s3,0.f);
    }
    __syncthreads();   // sync5: tst + z2 ready

    // ---- phase 5: coherent t store + out store ----
    {
      int nd2 = tid>>3, q = tid&7;
      int gi = n0+nd2;
      if(gi<cnt){
        long long v = node_list[base+gi];
        float* dp = tbuf + v*128 + q*16;
        f32x4 v0 = *(const f32x4*)&tst[nd2*132 + q*16];
        f32x4 v1 = *(const f32x4*)&tst[nd2*132 + q*16 + 4];
        f32x4 v2 = *(const f32x4*)&tst[nd2*132 + q*16 + 8];
        f32x4 v3 = *(const f32x4*)&tst[nd2*132 + q*16 + 12];
        row_store_coh(dp, v0,v1,v2,v3);
      }
    }
    if(tid<TN){
      int gi = n0+tid;
      if(gi<cnt){
        float s = b3[0];
        #pragma unroll 8
        for(int k=0;k<32;k++) s += z2l[tid*33+k]*w3l[k];
        out[node_list[base+gi]] = s;
      }
    }
    __syncthreads();   // sync6: every wave drains vmcnt -> stores device-visible

    // ---- publish: one RELAXED add on this level's counter ----
    if(tid==0){
      asm volatile("s_waitcnt vmcnt(0)" ::: "memory");
      __hip_atomic_fetch_add(&lvl_cnt[l*32], 1, __ATOMIC_RELAXED,
                             __HIP_MEMORY_SCOPE_AGENT);
    }
  }
}

extern "C" void kernel_launch(void* const* d_in, const int* in_sizes, int n_in,
                              void* d_out, int out_size, void* d_ws, size_t ws_size,
                              hipStream_t stream){
  const float* x     = (const float*)d_in[0];
  const int*   ei    = (const int*)  d_in[1];
  const int*   fl    = (const int*)  d_in[2];
  const float* emd_w = (const float*)d_in[4];
  const float* emd_b = (const float*)d_in[5];
  const float* agg_w = (const float*)d_in[6];
  const float* agg_b = (const float*)d_in[7];
  const float* w_ih  = (const float*)d_in[8];
  const float* w_hh  = (const float*)d_in[9];
  const float* b_ih  = (const float*)d_in[10];
  const float* b_hh  = (const float*)d_in[11];
  const float* w1    = (const float*)d_in[12];
  const float* b1    = (const float*)d_in[13];
  const float* w2    = (const float*)d_in[14];
  const float* b2    = (const float*)d_in[15];
  const float* w3    = (const float*)d_in[16];
  const float* b3    = (const float*)d_in[17];
  float* out = (float*)d_out;

  int N = in_sizes[2];
  int E = in_sizes[1]/2;
  int nb = (N + SCAN_CHUNK - 1)/SCAN_CHUNK;

  char* ws = (char*)d_ws;
  float* consts   = (float*)ws;                    // 4 KiB
  int*   ints     = (int*)(ws + 4096);             // 4 KiB (tile_off@96)
  int*   node_list= (int*)(ws + 8192);
  int*   node_rank= node_list + N;
  int*   indeg    = node_rank + N;                 // REAL indegree
  int*   cnum     = indeg + N;                     // const-edge count
  int*   row_ptr  = cnum + N;
  int*   fill     = row_ptr + N;
  int*   bsum     = fill + N;                      // 1024 block sums
  int*   lvl_cnt  = bsum + 1024;                   // 2048
  int*   edge_src = lvl_cnt + 2048;                // <= E ints (real edges only)
  size_t off0 = 8192 + ((size_t)6*N + 1024 + 2048 + (size_t)E)*4;
  off0 = (off0 + 255) & ~(size_t)255;
  unsigned short* wih_h = (unsigned short*)(ws + off0);       // 384*160
  unsigned short* wih_l = wih_h + G3*KP;
  unsigned short* agg_h = wih_l + G3*KP;                      // 128*128
  unsigned short* agg_l = agg_h + DHID*DHID;
  unsigned short* w1_h  = agg_l + DHID*DHID;                  // 32*128
  unsigned short* w1_l  = w1_h + 32*DHID;
  size_t off1 = off0 + (size_t)(2*G3*KP + 2*DHID*DHID + 2*32*DHID)*2;
  off1 = (off1 + 255) & ~(size_t)255;
  float* tbuf = (float*)(ws + off1);               // N*128 floats, never pre-initialized
  size_t need = off1 + (size_t)N*128*4;
  if(ws_size < need) return;

  k_zero0  <<<512,256,0,stream>>>(ints, lvl_cnt, indeg, cnum, fill, N);
  k_init   <<<1,128,0,stream>>>(emd_w,emd_b,agg_w,agg_b,w_hh,b_hh,w1,b1,w2,b2,w3,b3,consts);
  k_wprep  <<<256,256,0,stream>>>(w_ih,agg_w,w1,wih_h,wih_l,agg_h,agg_l,w1_h,w1_l);
  k_count  <<<512,256,0,stream>>>(fl,N,ints);
  k_prefix <<<1,1,0,stream>>>(ints);
  k_build  <<<512,256,0,stream>>>(fl,N,ints,node_list,node_rank);
  k_indeg  <<<1024,256,0,stream>>>(ei,fl,node_rank,ints,indeg,cnum,E);
  k_scan_a <<<nb,256,0,stream>>>(indeg,bsum,N);
  k_scan_b <<<1,256,0,stream>>>(bsum,nb);
  k_scan_c <<<nb,256,0,stream>>>(indeg,bsum,row_ptr,N);
  k_place  <<<1024,256,0,stream>>>(ei,fl,node_rank,ints,row_ptr,fill,edge_src,E);
  k_outc   <<<256,256,0,stream>>>(node_list,ints,out,consts);
  k_levels <<<GRID,BLK,0,stream>>>(x,node_list,row_ptr,indeg,cnum,edge_src,tbuf,
                                   wih_h,wih_l,agg_h,agg_l,w1_h,w1_l,
                                   b_ih,agg_b,b1,w2,b2,w3,b3,
                                   consts,out,ints,lvl_cnt);
}

// Round 14
// 883.665 us; speedup vs baseline: 1.3451x; 1.0658x over previous
//
#include <hip/hip_runtime.h>
#include <math.h>

// Problem dims (fixed by the reference file)
#define DHID 128
#define DXIN 16
#define DIN  144   // DHID + DXIN
#define G3   384   // 3*DHID
#define NLEV 16
#define SCAN_CHUNK 2048
#define KP   160   // GEMM1 K padded to mult of 32
#define AS   168   // A LDS row stride in bf16 units
#define HS   136   // H LDS row stride in bf16 units
#define TN   64    // tile nodes
#define GRID 256
#define BLK  512

typedef __attribute__((ext_vector_type(8))) short short8_t;
typedef __attribute__((ext_vector_type(4))) float f32x4;

__device__ __forceinline__ float sigmoidf_(float v){ return 1.0f/(1.0f + __expf(-v)); }
__device__ __forceinline__ float tanhf_(float v){
  v = fminf(fmaxf(v,-15.f),15.f);
  float e = __expf(2.f*v);
  return (e-1.f)/(e+1.f);
}
__device__ __forceinline__ unsigned short f2bf(float f){
  unsigned u = __float_as_uint(f);
  u = u + 0x7FFFu + ((u>>16)&1u);
  return (unsigned short)(u>>16);
}
__device__ __forceinline__ float bf2f(unsigned short h){
  return __uint_as_float(((unsigned)h)<<16);
}

// coherent (device-scope, L2-bypass) 64B row-quarter load (r9-proven, low-reg)
__device__ __forceinline__ void row_load_coh(const float* p,
                                             f32x4& v0, f32x4& v1, f32x4& v2, f32x4& v3){
  asm volatile(
    "global_load_dwordx4 %0, %4, off sc0 sc1\n\t"
    "global_load_dwordx4 %1, %4, off offset:16 sc0 sc1\n\t"
    "global_load_dwordx4 %2, %4, off offset:32 sc0 sc1\n\t"
    "global_load_dwordx4 %3, %4, off offset:48 sc0 sc1\n\t"
    "s_waitcnt vmcnt(0)"
    : "=&v"(v0), "=&v"(v1), "=&v"(v2), "=&v"(v3)
    : "v"(p)
    : "memory");
}
__device__ __forceinline__ void row_store_coh(float* p,
                                              f32x4 v0, f32x4 v1, f32x4 v2, f32x4 v3){
  asm volatile(
    "global_store_dwordx4 %0, %1, off sc0 sc1\n\t"
    "global_store_dwordx4 %0, %2, off offset:16 sc0 sc1\n\t"
    "global_store_dwordx4 %0, %3, off offset:32 sc0 sc1\n\t"
    "global_store_dwordx4 %0, %4, off offset:48 sc0 sc1"
    :: "v"(p), "v"(v0), "v"(v1), "v"(v2), "v"(v3)
    : "memory");
}

// ---------------- zero counters / indeg / cnum / fill / level counters ----------
__global__ void k_zero0(int* ints, int* lvl_cnt, int* indeg, int* cnum, int* fill, int N){
  int i = blockIdx.x*blockDim.x + threadIdx.x;
  int stride = gridDim.x*blockDim.x;
  if(i<1024) ints[i]=0;
  if(i<2048) lvl_cnt[i]=0;
  for(int j=i;j<N;j+=stride){ indeg[j]=0; cnum[j]=0; fill[j]=0; }
}

// ---------------- precompute h_init, t_init, gh_init, c0 ----------------
// consts (floats): [0..127]=h_init [128..255]=t_init [256..639]=gh(r,z,n) [640]=c0
__global__ void k_init(const float* emd_w, const float* emd_b,
                       const float* agg_w, const float* agg_b,
                       const float* w_hh, const float* b_hh,
                       const float* w1,const float* b1,const float* w2,const float* b2,
                       const float* w3,const float* b3,
                       float* consts){
  __shared__ float hl[128];
  __shared__ float z1[32];
  __shared__ float z2[32];
  int t = threadIdx.x;
  float h = emd_w[t] + emd_b[t];
  hl[t] = h; consts[t] = h;
  __syncthreads();
  float s = agg_b[t];
  for(int k=0;k<128;k++) s += agg_w[t*128+k]*hl[k];
  consts[128+t] = s;
  for(int g=t; g<G3; g+=128){
    float q = b_hh[g];
    for(int k=0;k<128;k++) q += w_hh[g*128+k]*hl[k];
    consts[256+g] = q;
  }
  if(t<32){
    float a = b1[t];
    for(int k=0;k<128;k++) a += w1[t*128+k]*hl[k];
    z1[t] = fmaxf(a,0.f);
  }
  __syncthreads();
  if(t<32){
    float a = b2[t];
    for(int k=0;k<32;k++) a += w2[t*32+k]*z1[k];
    z2[t] = fmaxf(a,0.f);
  }
  __syncthreads();
  if(t==0){
    float a = b3[0];
    for(int k=0;k<32;k++) a += w3[k]*z2[k];
    consts[640] = a;
  }
}

// ---------------- split weights into bf16 hi/lo ----------------
__global__ void k_wprep(const float* w_ih, const float* agg_w, const float* w1,
                        unsigned short* wih_h, unsigned short* wih_l,
                        unsigned short* agg_h, unsigned short* agg_l,
                        unsigned short* w1_h, unsigned short* w1_l){
  int i = blockIdx.x*blockDim.x + threadIdx.x;
  int stride = gridDim.x*blockDim.x;
  for(int idx=i; idx<G3*KP; idx+=stride){
    int g = idx/KP, k = idx - g*KP;
    float v = (k<DIN)? w_ih[g*DIN+k] : 0.f;
    unsigned short h = f2bf(v);
    wih_h[idx]=h; wih_l[idx]=f2bf(v-bf2f(h));
  }
  for(int idx=i; idx<DHID*DHID; idx+=stride){
    float v = agg_w[idx];
    unsigned short h=f2bf(v); agg_h[idx]=h; agg_l[idx]=f2bf(v-bf2f(h));
  }
  for(int idx=i; idx<32*DHID; idx+=stride){
    float v = w1[idx];
    unsigned short h=f2bf(v); w1_h[idx]=h; w1_l[idx]=f2bf(v-bf2f(h));
  }
}

// ---------------- node histogram by level ----------------
// ints: node_cnt@0(16) node_off@32(17) node_fill@64(16) tile_off@96(17)
__global__ void k_count(const int* fl, int N, int* ints){
  __shared__ int hn[16];
  int tid = threadIdx.x;
  if(tid<16) hn[tid]=0;
  __syncthreads();
  int i = blockIdx.x*blockDim.x+tid;
  int stride = gridDim.x*blockDim.x;
  for(int j=i;j<N;j+=stride) atomicAdd(&hn[fl[j]], 1);
  __syncthreads();
  if(tid<16 && hn[tid]) atomicAdd(&ints[tid], hn[tid]);
}

__global__ void k_prefix(int* ints){
  if(threadIdx.x==0 && blockIdx.x==0){
    int o=0;
    for(int l=0;l<NLEV;l++){ ints[32+l]=o; ints[64+l]=o; o+=ints[l]; }
    ints[32+NLEV]=o;
    int to=0;
    ints[96]=0;
    for(int l=1;l<NLEV;l++){ ints[96+l]=to; to += (ints[l]+TN-1)/TN; }
    ints[96+NLEV]=to;   // total tiles
  }
}

// Two-pass per-block counting sort of nodes by level.
__global__ void k_build(const int* fl, int N, int* ints,
                        int* node_list, int* node_rank){
  __shared__ int h[16], base[16];
  int tid = threadIdx.x;
  int nchunk = (N + gridDim.x - 1)/gridDim.x;
  int lo = blockIdx.x*nchunk;
  int hi = lo + nchunk; if(hi>N) hi=N;
  if(tid<16) h[tid]=0;
  __syncthreads();
  for(int j=lo+tid; j<hi; j+=blockDim.x) atomicAdd(&h[fl[j]],1);
  __syncthreads();
  if(tid<16){ base[tid] = h[tid] ? atomicAdd(&ints[64+tid], h[tid]) : 0; h[tid]=0; }
  __syncthreads();
  for(int j=lo+tid; j<hi; j+=blockDim.x){
    int lev = fl[j];
    int pos = base[lev] + atomicAdd(&h[lev],1);
    node_list[pos]=j;
    node_rank[j]=pos-ints[32+lev];
  }
}

// ------ indegree split: REAL edges (1<=fl[s]<fl[tg]) vs CONST edges (count only) --
__global__ void k_indeg(const int* ei, const int* fl, const int* node_rank,
                        const int* ints, int* indeg, int* cnum, int E){
  int i = blockIdx.x*blockDim.x+threadIdx.x;
  int stride = gridDim.x*blockDim.x;
  for(int e=i;e<E;e+=stride){
    int s  = ei[e];
    int tg = ei[E+e];
    int flt = fl[tg];
    int p = ints[32+flt] + node_rank[tg];
    int fls = fl[s];
    if(fls>=1 && fls<flt) atomicAdd(&indeg[p],1);
    else                  atomicAdd(&cnum[p],1);
  }
}

// ---------------- hierarchical exclusive scan of indeg -> row_ptr ----------------
__global__ void k_scan_a(const int* indeg, int* bsum, int N){
  __shared__ int ts[256];
  int b=blockIdx.x, t=threadIdx.x;
  int base=b*SCAN_CHUNK+t*8; int s=0;
  for(int j=0;j<8;j++){ int idx=base+j; if(idx<N) s+=indeg[idx]; }
  ts[t]=s; __syncthreads();
  for(int off=128;off>0;off>>=1){ if(t<off) ts[t]+=ts[t+off]; __syncthreads(); }
  if(t==0) bsum[b]=ts[0];
}
__global__ void k_scan_b(int* bsum, int nb){
  __shared__ int ls[256];
  int t=threadIdx.x;
  int v = (t<nb)? bsum[t]:0; ls[t]=v; __syncthreads();
  for(int off=1;off<256;off<<=1){
    int add = (t>=off)? ls[t-off]:0;
    __syncthreads();
    ls[t]+=add;
    __syncthreads();
  }
  if(t<nb) bsum[t] = ls[t]-v;   // exclusive
}
__global__ void k_scan_c(const int* indeg, const int* bsum, int* row_ptr, int N){
  __shared__ int ts[256];
  int b=blockIdx.x, t=threadIdx.x;
  int base=b*SCAN_CHUNK+t*8;
  int v[8]; int s=0;
  for(int j=0;j<8;j++){ int idx=base+j; v[j]=(idx<N)?indeg[idx]:0; s+=v[j]; }
  ts[t]=s; __syncthreads();
  for(int off=1;off<256;off<<=1){
    int add = (t>=off)? ts[t-off]:0;
    __syncthreads();
    ts[t]+=add;
    __syncthreads();
  }
  int excl = bsum[b] + ((t>0)? ts[t-1]:0);
  for(int j=0;j<8;j++){ int idx=base+j; if(idx<N) row_ptr[idx]=excl; excl+=v[j]; }
}

// ------- place ONLY real edges into CSR -------
__global__ void k_place(const int* ei, const int* fl, const int* node_rank,
                        const int* ints, const int* row_ptr, int* fill,
                        int* edge_src, int E){
  int i = blockIdx.x*blockDim.x+threadIdx.x;
  int stride = gridDim.x*blockDim.x;
  for(int e=i;e<E;e+=stride){
    int s  = ei[e];
    int tg = ei[E+e];
    int flt = fl[tg];
    int fls = fl[s];
    if(fls>=1 && fls<flt){
      int p = ints[32+flt] + node_rank[tg];
      int slot = atomicAdd(&fill[p],1);
      edge_src[row_ptr[p]+slot] = s;
    }
  }
}

// ---------------- out = c0 for LEVEL-0 nodes only (never updated later) ---------
__global__ void k_outc(const int* node_list, const int* ints,
                       float* out, const float* consts){
  int cnt0 = ints[0];
  float c0 = consts[640];
  int i = blockIdx.x*blockDim.x+threadIdx.x;
  int stride = gridDim.x*blockDim.x;
  for(int j=i;j<cnt0;j+=stride) out[node_list[j]]=c0;
}

// ================= persistent kernel: weights streamed from L2 per k-step ========
// 256 blocks x 512 threads, 1 block/CU. NO persistent weight registers — the bf16
// weight tables (245 KB + 64 KB + 16 KB) stay L2-resident because tbuf uses
// sc0|sc1 L2-BYPASS ops (the r4 failure — tbuf stream evicting weights — cannot
// recur). Per kk-step each thread loads its 6 fragment (96 B) from L2 right
// before 9 MFMAs; 8 waves hide the L2 latency. Peak live regs ~130 -> no spills.
__global__ __launch_bounds__(BLK,1) void k_levels(
    const float* __restrict__ x, const int* __restrict__ node_list,
    const int* __restrict__ row_ptr, const int* __restrict__ indeg,
    const int* __restrict__ cnum, const int* __restrict__ edge_src,
    float* __restrict__ tbuf,
    const unsigned short* __restrict__ wih_h, const unsigned short* __restrict__ wih_l,
    const unsigned short* __restrict__ agg_h, const unsigned short* __restrict__ agg_l,
    const unsigned short* __restrict__ w1_h, const unsigned short* __restrict__ w1_l,
    const float* __restrict__ b_ih, const float* __restrict__ agg_b,
    const float* __restrict__ b1, const float* __restrict__ w2,
    const float* __restrict__ b2, const float* __restrict__ w3,
    const float* __restrict__ b3,
    const float* __restrict__ consts, float* __restrict__ out,
    int* ints, int* lvl_cnt)
{
  __shared__ __align__(16) unsigned char smem[64256];
  unsigned short* Ahi = (unsigned short*)smem;
  unsigned short* Alo = (unsigned short*)(smem + 21504);
  unsigned short* Hhi = (unsigned short*)smem;
  unsigned short* Hlo = (unsigned short*)(smem + 17408);
  float* tst = (float*)smem;                 // [64][132]
  float* z1l = (float*)(smem + 43008);
  float* z2l = (float*)(smem + 51456);
  float* w2t = (float*)(smem + 59904);
  float* w3l = (float*)(smem + 64128);

  int tid = threadIdx.x;
  int wv = tid>>6, ln = tid&63, lr = ln&15, lq = ln>>4;
  int cgo = tid&7, nd = tid>>3;    // gather: 8 thr/node, 16 dims each
  int d = wv*16 + lr;              // this lane's output dim (GEMM1/2)
  int mB = wv>>1, nB = wv&1;       // MLP1 sub-tile

  float ghr=consts[256+d], ghz=consts[384+d], ghn=consts[512+d], h0c=consts[d];
  float bir=b_ih[d], biz=b_ih[128+d], bin_=b_ih[256+d], ab2=agg_b[d];
  float b1o = b1[nB*16+lr];
  f32x4 ti[4];
  { const f32x4* c4=(const f32x4*)(consts+128);
    #pragma unroll
    for(int q=0;q<4;q++) ti[q]=c4[cgo*4+q]; }

  // ---- stage small fp32 weights ----
  for(int idx=tid; idx<1024; idx+=BLK){ int j=idx>>5, k=idx&31;  w2t[k*33+j]=w2[idx]; }
  if(tid<32) w3l[tid]=w3[tid];
  __syncthreads();

  int total_tiles = ints[96+NLEV];
  int l = 1;

  for(int T = blockIdx.x; T < total_tiles; T += GRID){
    while(l < NLEV-1 && T >= ints[96+l+1]) l++;
    int cnt  = ints[l];
    int base = ints[32+l];
    int n0 = (T - ints[96+l])*TN;

    // ---- x into A cols 128..143, zero 144..159 (pre-wait; no tbuf access) ----
    if(tid<256){
      int i = tid>>2, j = tid&3;
      int gi = n0+i;
      float4 xv = make_float4(0.f,0.f,0.f,0.f);
      if(gi<cnt) xv = ((const float4*)x)[node_list[base+gi]*4 + j];
      float vv[4]={xv.x,xv.y,xv.z,xv.w};
      #pragma unroll
      for(int q=0;q<4;q++){
        unsigned short h=f2bf(vv[q]);
        Ahi[i*AS+128+j*4+q]=h;
        Alo[i*AS+128+j*4+q]=f2bf(vv[q]-bf2f(h));
      }
      #pragma unroll
      for(int q=0;q<4;q++){ Ahi[i*AS+144+j*4+q]=0; Alo[i*AS+144+j*4+q]=0; }
    }

    // ---- wait: previous level fully done (single counter, backoff poll) ----
    if(tid==0 && l>1){
      int need = ints[96+l] - ints[96+l-1];
      if(need>0){
        int it=0;
        while(__hip_atomic_load(&lvl_cnt[(l-1)*32], __ATOMIC_RELAXED,
                                __HIP_MEMORY_SCOPE_AGENT) < need){
          if(it<8) __builtin_amdgcn_s_sleep(8);
          else     __builtin_amdgcn_s_sleep(32);
          it++;
        }
      }
    }
    __syncthreads();

    // ---- phase 0: gather msg (real edges only) -> bf16 hi/lo into A ----
    {
      f32x4 a[4];
      int gi = n0+nd;
      if(gi<cnt){
        int p = base+gi;
        int r0 = row_ptr[p], dr = indeg[p];
        float fdc = (float)cnum[p];
        #pragma unroll
        for(int q=0;q<4;q++) a[q] = fdc*ti[q];
        for(int e=0;e<dr;e++){
          int s = edge_src[r0+e];
          const float* sp = tbuf + ((long long)s*128 + cgo*16);
          f32x4 v0,v1,v2,v3;
          row_load_coh(sp, v0,v1,v2,v3);
          a[0]+=v0; a[1]+=v1; a[2]+=v2; a[3]+=v3;
        }
      } else {
        #pragma unroll
        for(int q=0;q<4;q++) a[q]=(f32x4){0.f,0.f,0.f,0.f};
      }
      #pragma unroll
      for(int hf=0; hf<2; hf++){
        short8_t hv, lv;
        #pragma unroll
        for(int j=0;j<8;j++){
          float v = a[hf*2 + (j>>2)][j&3];
          unsigned short h = f2bf(v);
          hv[j]=(short)h; lv[j]=(short)f2bf(v-bf2f(h));
        }
        *(short8_t*)&Ahi[nd*AS + cgo*16 + hf*8] = hv;
        *(short8_t*)&Alo[nd*AS + cgo*16 + hf*8] = lv;
      }
    }
    __syncthreads();   // sync1: A ready

    // ---- phase 1: GEMM1 (bf16x3 MFMA, weights streamed from L2 per kk) ----
    f32x4 Ar[4],Az[4],An[4];
    #pragma unroll
    for(int m=0;m<4;m++){
      Ar[m]=(f32x4){bir,bir,bir,bir};
      Az[m]=(f32x4){biz,biz,biz,biz};
      An[m]=(f32x4){bin_,bin_,bin_,bin_};
    }
    #pragma unroll
    for(int kk=0;kk<5;kk++){
      const unsigned short* wb = wih_h + (long long)d*KP + kk*32 + lq*8;
      const unsigned short* lb = wih_l + (long long)d*KP + kk*32 + lq*8;
      short8_t wrh = *(const short8_t*)wb;
      short8_t wrl = *(const short8_t*)lb;
      short8_t wzh = *(const short8_t*)(wb + (long long)128*KP);
      short8_t wzl = *(const short8_t*)(lb + (long long)128*KP);
      short8_t wnh = *(const short8_t*)(wb + (long long)256*KP);
      short8_t wnl = *(const short8_t*)(lb + (long long)256*KP);
      short8_t ah[4], al[4];
      #pragma unroll
      for(int m=0;m<4;m++){
        int off = (m*16+lr)*AS + kk*32 + lq*8;
        ah[m]=*(const short8_t*)&Ahi[off];
        al[m]=*(const short8_t*)&Alo[off];
      }
      #pragma unroll
      for(int m=0;m<4;m++){
        Ar[m]=__builtin_amdgcn_mfma_f32_16x16x32_bf16(ah[m],wrh,Ar[m],0,0,0);
        Ar[m]=__builtin_amdgcn_mfma_f32_16x16x32_bf16(ah[m],wrl,Ar[m],0,0,0);
        Ar[m]=__builtin_amdgcn_mfma_f32_16x16x32_bf16(al[m],wrh,Ar[m],0,0,0);
        Az[m]=__builtin_amdgcn_mfma_f32_16x16x32_bf16(ah[m],wzh,Az[m],0,0,0);
        Az[m]=__builtin_amdgcn_mfma_f32_16x16x32_bf16(ah[m],wzl,Az[m],0,0,0);
        Az[m]=__builtin_amdgcn_mfma_f32_16x16x32_bf16(al[m],wzh,Az[m],0,0,0);
        An[m]=__builtin_amdgcn_mfma_f32_16x16x32_bf16(ah[m],wnh,An[m],0,0,0);
        An[m]=__builtin_amdgcn_mfma_f32_16x16x32_bf16(ah[m],wnl,An[m],0,0,0);
        An[m]=__builtin_amdgcn_mfma_f32_16x16x32_bf16(al[m],wnh,An[m],0,0,0);
      }
    }
    __syncthreads();   // sync2: all A reads done, H may overwrite

    // ---- phase 2: GRU gates -> H (bf16 hi/lo over A region) ----
    #pragma unroll
    for(int m=0;m<4;m++){
      #pragma unroll
      for(int j=0;j<4;j++){
        float r = sigmoidf_(Ar[m][j] + ghr);
        float z = sigmoidf_(Az[m][j] + ghz);
        float n = tanhf_(An[m][j] + r*ghn);
        float h = (1.f-z)*n + z*h0c;
        int node = m*16 + lq*4 + j;
        unsigned short hb = f2bf(h);
        Hhi[node*HS + d] = hb;
        Hlo[node*HS + d] = f2bf(h - bf2f(hb));
      }
    }
    __syncthreads();   // sync3: H ready

    // ---- phase 3: GEMM2 (t) + MLP1 (z1), weights streamed from L2 per kk ----
    f32x4 T2[4];
    #pragma unroll
    for(int m=0;m<4;m++) T2[m]=(f32x4){ab2,ab2,ab2,ab2};
    f32x4 M1 = (f32x4){b1o,b1o,b1o,b1o};
    #pragma unroll
    for(int kk=0;kk<4;kk++){
      int ro  = d*DHID + kk*32 + lq*8;
      short8_t agh = *(const short8_t*)&agg_h[ro];
      short8_t agl = *(const short8_t*)&agg_l[ro];
      int r1  = (nB*16+lr)*DHID + kk*32 + lq*8;
      short8_t w1h = *(const short8_t*)&w1_h[r1];
      short8_t w1l = *(const short8_t*)&w1_l[r1];
      short8_t hh[4], hl2[4];
      #pragma unroll
      for(int m=0;m<4;m++){
        int off = (m*16+lr)*HS + kk*32 + lq*8;
        hh[m]=*(const short8_t*)&Hhi[off];
        hl2[m]=*(const short8_t*)&Hlo[off];
      }
      #pragma unroll
      for(int m=0;m<4;m++){
        T2[m]=__builtin_amdgcn_mfma_f32_16x16x32_bf16(hh[m], agh,T2[m],0,0,0);
        T2[m]=__builtin_amdgcn_mfma_f32_16x16x32_bf16(hh[m], agl,T2[m],0,0,0);
        T2[m]=__builtin_amdgcn_mfma_f32_16x16x32_bf16(hl2[m],agh,T2[m],0,0,0);
      }
      M1=__builtin_amdgcn_mfma_f32_16x16x32_bf16(hh[mB], w1h,M1,0,0,0);
      M1=__builtin_amdgcn_mfma_f32_16x16x32_bf16(hh[mB], w1l,M1,0,0,0);
      M1=__builtin_amdgcn_mfma_f32_16x16x32_bf16(hl2[mB],w1h,M1,0,0,0);
    }
    #pragma unroll
    for(int j=0;j<4;j++){
      int node = mB*16 + lq*4 + j;
      z1l[node*33 + nB*16+lr] = fmaxf(M1[j],0.f);
    }
    __syncthreads();   // sync4: H reads done; tst may overwrite; z1 ready

    // ---- phase 4: stage t into LDS (fp32) + MLP2 (VALU) ----
    #pragma unroll
    for(int m=0;m<4;m++){
      #pragma unroll
      for(int j=0;j<4;j++){
        int node = m*16 + lq*4 + j;
        tst[node*132 + d] = T2[m][j];
      }
    }
    {
      int ndl = tid>>3, jo = (tid&7)*4;
      float s0=b2[jo], s1=b2[jo+1], s2=b2[jo+2], s3=b2[jo+3];
      #pragma unroll 8
      for(int k=0;k<32;k++){
        float zv = z1l[ndl*33+k];
        s0 += zv*w2t[k*33+jo];
        s1 += zv*w2t[k*33+jo+1];
        s2 += zv*w2t[k*33+jo+2];
        s3 += zv*w2t[k*33+jo+3];
      }
      z2l[ndl*33+jo]   = fmaxf(s0,0.f);
      z2l[ndl*33+jo+1] = fmaxf(s1,0.f);
      z2l[ndl*33+jo+2] = fmaxf(s2,0.f);
      z2l[ndl*33+jo+3] = fmaxf(s3,0.f);
    }
    __syncthreads();   // sync5: tst + z2 ready

    // ---- phase 5: coherent t store + out store ----
    {
      int nd2 = tid>>3, q = tid&7;
      int gi = n0+nd2;
      if(gi<cnt){
        long long v = node_list[base+gi];
        float* dp = tbuf + v*128 + q*16;
        f32x4 v0 = *(const f32x4*)&tst[nd2*132 + q*16];
        f32x4 v1 = *(const f32x4*)&tst[nd2*132 + q*16 + 4];
        f32x4 v2 = *(const f32x4*)&tst[nd2*132 + q*16 + 8];
        f32x4 v3 = *(const f32x4*)&tst[nd2*132 + q*16 + 12];
        row_store_coh(dp, v0,v1,v2,v3);
      }
    }
    if(tid<TN){
      int gi = n0+tid;
      if(gi<cnt){
        float s = b3[0];
        #pragma unroll 8
        for(int k=0;k<32;k++) s += z2l[tid*33+k]*w3l[k];
        out[node_list[base+gi]] = s;
      }
    }
    __syncthreads();   // sync6: every wave drains vmcnt -> stores device-visible

    // ---- publish: one RELAXED add on this level's counter ----
    if(tid==0){
      asm volatile("s_waitcnt vmcnt(0)" ::: "memory");
      __hip_atomic_fetch_add(&lvl_cnt[l*32], 1, __ATOMIC_RELAXED,
                             __HIP_MEMORY_SCOPE_AGENT);
    }
  }
}

extern "C" void kernel_launch(void* const* d_in, const int* in_sizes, int n_in,
                              void* d_out, int out_size, void* d_ws, size_t ws_size,
                              hipStream_t stream){
  const float* x     = (const float*)d_in[0];
  const int*   ei    = (const int*)  d_in[1];
  const int*   fl    = (const int*)  d_in[2];
  const float* emd_w = (const float*)d_in[4];
  const float* emd_b = (const float*)d_in[5];
  const float* agg_w = (const float*)d_in[6];
  const float* agg_b = (const float*)d_in[7];
  const float* w_ih  = (const float*)d_in[8];
  const float* w_hh  = (const float*)d_in[9];
  const float* b_ih  = (const float*)d_in[10];
  const float* b_hh  = (const float*)d_in[11];
  const float* w1    = (const float*)d_in[12];
  const float* b1    = (const float*)d_in[13];
  const float* w2    = (const float*)d_in[14];
  const float* b2    = (const float*)d_in[15];
  const float* w3    = (const float*)d_in[16];
  const float* b3    = (const float*)d_in[17];
  float* out = (float*)d_out;

  int N = in_sizes[2];
  int E = in_sizes[1]/2;
  int nb = (N + SCAN_CHUNK - 1)/SCAN_CHUNK;

  char* ws = (char*)d_ws;
  float* consts   = (float*)ws;                    // 4 KiB
  int*   ints     = (int*)(ws + 4096);             // 4 KiB (tile_off@96)
  int*   node_list= (int*)(ws + 8192);
  int*   node_rank= node_list + N;
  int*   indeg    = node_rank + N;                 // REAL indegree
  int*   cnum     = indeg + N;                     // const-edge count
  int*   row_ptr  = cnum + N;
  int*   fill     = row_ptr + N;
  int*   bsum     = fill + N;                      // 1024 block sums
  int*   lvl_cnt  = bsum + 1024;                   // 2048
  int*   edge_src = lvl_cnt + 2048;                // <= E ints (real edges only)
  size_t off0 = 8192 + ((size_t)6*N + 1024 + 2048 + (size_t)E)*4;
  off0 = (off0 + 255) & ~(size_t)255;
  unsigned short* wih_h = (unsigned short*)(ws + off0);       // 384*160
  unsigned short* wih_l = wih_h + G3*KP;
  unsigned short* agg_h = wih_l + G3*KP;                      // 128*128
  unsigned short* agg_l = agg_h + DHID*DHID;
  unsigned short* w1_h  = agg_l + DHID*DHID;                  // 32*128
  unsigned short* w1_l  = w1_h + 32*DHID;
  size_t off1 = off0 + (size_t)(2*G3*KP + 2*DHID*DHID + 2*32*DHID)*2;
  off1 = (off1 + 255) & ~(size_t)255;
  float* tbuf = (float*)(ws + off1);               // N*128 floats, never pre-initialized
  size_t need = off1 + (size_t)N*128*4;
  if(ws_size < need) return;

  k_zero0  <<<512,256,0,stream>>>(ints, lvl_cnt, indeg, cnum, fill, N);
  k_init   <<<1,128,0,stream>>>(emd_w,emd_b,agg_w,agg_b,w_hh,b_hh,w1,b1,w2,b2,w3,b3,consts);
  k_wprep  <<<256,256,0,stream>>>(w_ih,agg_w,w1,wih_h,wih_l,agg_h,agg_l,w1_h,w1_l);
  k_count  <<<512,256,0,stream>>>(fl,N,ints);
  k_prefix <<<1,1,0,stream>>>(ints);
  k_build  <<<512,256,0,stream>>>(fl,N,ints,node_list,node_rank);
  k_indeg  <<<1024,256,0,stream>>>(ei,fl,node_rank,ints,indeg,cnum,E);
  k_scan_a <<<nb,256,0,stream>>>(indeg,bsum,N);
  k_scan_b <<<1,256,0,stream>>>(bsum,nb);
  k_scan_c <<<nb,256,0,stream>>>(indeg,bsum,row_ptr,N);
  k_place  <<<1024,256,0,stream>>>(ei,fl,node_rank,ints,row_ptr,fill,edge_src,E);
  k_outc   <<<256,256,0,stream>>>(node_list,ints,out,consts);
  k_levels <<<GRID,BLK,0,stream>>>(x,node_list,row_ptr,indeg,cnum,edge_src,tbuf,
                                   wih_h,wih_l,agg_h,agg_l,w1_h,w1_l,
                                   b_ih,agg_b,b1,w2,b2,w3,b3,
                                   consts,out,ints,lvl_cnt);
}

// Round 15
// 388.495 us; speedup vs baseline: 3.0596x; 2.2746x over previous
//
#include <hip/hip_runtime.h>
#include <math.h>

// Problem dims (fixed by the reference file)
#define DHID 128
#define DXIN 16
#define DIN  144   // DHID + DXIN
#define G3   384   // 3*DHID
#define NLEV 16
#define SCAN_CHUNK 2048
#define KP   160   // GEMM1 K padded to mult of 32
#define AS   168   // A LDS row stride in bf16 units
#define HS   136   // H LDS row stride in bf16 units
#define TN   64    // tile nodes
#define GRID 256
#define BLK  512

typedef __attribute__((ext_vector_type(8))) short short8_t;
typedef __attribute__((ext_vector_type(4))) float f32x4;

__device__ __forceinline__ float sigmoidf_(float v){ return 1.0f/(1.0f + __expf(-v)); }
__device__ __forceinline__ float tanhf_(float v){
  v = fminf(fmaxf(v,-15.f),15.f);
  float e = __expf(2.f*v);
  return (e-1.f)/(e+1.f);
}
__device__ __forceinline__ unsigned short f2bf(float f){
  unsigned u = __float_as_uint(f);
  u = u + 0x7FFFu + ((u>>16)&1u);
  return (unsigned short)(u>>16);
}
__device__ __forceinline__ float bf2f(unsigned short h){
  return __uint_as_float(((unsigned)h)<<16);
}

// coherent (device-scope, L2-bypass) 64B row load, single (tail case)
__device__ __forceinline__ void row_load_coh(const float* p,
                                             f32x4& v0, f32x4& v1, f32x4& v2, f32x4& v3){
  asm volatile(
    "global_load_dwordx4 %0, %4, off sc0 sc1\n\t"
    "global_load_dwordx4 %1, %4, off offset:16 sc0 sc1\n\t"
    "global_load_dwordx4 %2, %4, off offset:32 sc0 sc1\n\t"
    "global_load_dwordx4 %3, %4, off offset:48 sc0 sc1\n\t"
    "s_waitcnt vmcnt(0)"
    : "=&v"(v0), "=&v"(v1), "=&v"(v2), "=&v"(v3)
    : "v"(p)
    : "memory");
}

// ---------------- zero counters / indeg / cnum / fill / level counters ----------
__global__ void k_zero0(int* ints, int* lvl_cnt, int* indeg, int* cnum, int* fill, int N){
  int i = blockIdx.x*blockDim.x + threadIdx.x;
  int stride = gridDim.x*blockDim.x;
  if(i<1024) ints[i]=0;
  if(i<2048) lvl_cnt[i]=0;
  for(int j=i;j<N;j+=stride){ indeg[j]=0; cnum[j]=0; fill[j]=0; }
}

// ---------------- precompute h_init, t_init, gh_init, c0 ----------------
// consts (floats): [0..127]=h_init [128..255]=t_init [256..639]=gh(r,z,n) [640]=c0
__global__ void k_init(const float* emd_w, const float* emd_b,
                       const float* agg_w, const float* agg_b,
                       const float* w_hh, const float* b_hh,
                       const float* w1,const float* b1,const float* w2,const float* b2,
                       const float* w3,const float* b3,
                       float* consts){
  __shared__ float hl[128];
  __shared__ float z1[32];
  __shared__ float z2[32];
  int t = threadIdx.x;
  float h = emd_w[t] + emd_b[t];
  hl[t] = h; consts[t] = h;
  __syncthreads();
  float s = agg_b[t];
  for(int k=0;k<128;k++) s += agg_w[t*128+k]*hl[k];
  consts[128+t] = s;
  for(int g=t; g<G3; g+=128){
    float q = b_hh[g];
    for(int k=0;k<128;k++) q += w_hh[g*128+k]*hl[k];
    consts[256+g] = q;
  }
  if(t<32){
    float a = b1[t];
    for(int k=0;k<128;k++) a += w1[t*128+k]*hl[k];
    z1[t] = fmaxf(a,0.f);
  }
  __syncthreads();
  if(t<32){
    float a = b2[t];
    for(int k=0;k<32;k++) a += w2[t*32+k]*z1[k];
    z2[t] = fmaxf(a,0.f);
  }
  __syncthreads();
  if(t==0){
    float a = b3[0];
    for(int k=0;k<32;k++) a += w3[k]*z2[k];
    consts[640] = a;
  }
}

// ---------------- split weights into bf16 hi/lo ----------------
__global__ void k_wprep(const float* w_ih, const float* agg_w, const float* w1,
                        unsigned short* wih_h, unsigned short* wih_l,
                        unsigned short* agg_h, unsigned short* agg_l,
                        unsigned short* w1_h, unsigned short* w1_l){
  int i = blockIdx.x*blockDim.x + threadIdx.x;
  int stride = gridDim.x*blockDim.x;
  for(int idx=i; idx<G3*KP; idx+=stride){
    int g = idx/KP, k = idx - g*KP;
    float v = (k<DIN)? w_ih[g*DIN+k] : 0.f;
    unsigned short h = f2bf(v);
    wih_h[idx]=h; wih_l[idx]=f2bf(v-bf2f(h));
  }
  for(int idx=i; idx<DHID*DHID; idx+=stride){
    float v = agg_w[idx];
    unsigned short h=f2bf(v); agg_h[idx]=h; agg_l[idx]=f2bf(v-bf2f(h));
  }
  for(int idx=i; idx<32*DHID; idx+=stride){
    float v = w1[idx];
    unsigned short h=f2bf(v); w1_h[idx]=h; w1_l[idx]=f2bf(v-bf2f(h));
  }
}

// ---------------- node histogram by level ----------------
// ints: node_cnt@0(16) node_off@32(17) node_fill@64(16) tile_off@96(17)
__global__ void k_count(const int* fl, int N, int* ints){
  __shared__ int hn[16];
  int tid = threadIdx.x;
  if(tid<16) hn[tid]=0;
  __syncthreads();
  int i = blockIdx.x*blockDim.x+tid;
  int stride = gridDim.x*blockDim.x;
  for(int j=i;j<N;j+=stride) atomicAdd(&hn[fl[j]], 1);
  __syncthreads();
  if(tid<16 && hn[tid]) atomicAdd(&ints[tid], hn[tid]);
}

__global__ void k_prefix(int* ints){
  if(threadIdx.x==0 && blockIdx.x==0){
    int o=0;
    for(int l=0;l<NLEV;l++){ ints[32+l]=o; ints[64+l]=o; o+=ints[l]; }
    ints[32+NLEV]=o;
    int to=0;
    ints[96]=0;
    for(int l=1;l<NLEV;l++){ ints[96+l]=to; to += (ints[l]+TN-1)/TN; }
    ints[96+NLEV]=to;   // total tiles
  }
}

// Two-pass per-block counting sort of nodes by level.
__global__ void k_build(const int* fl, int N, int* ints,
                        int* node_list, int* node_rank){
  __shared__ int h[16], base[16];
  int tid = threadIdx.x;
  int nchunk = (N + gridDim.x - 1)/gridDim.x;
  int lo = blockIdx.x*nchunk;
  int hi = lo + nchunk; if(hi>N) hi=N;
  if(tid<16) h[tid]=0;
  __syncthreads();
  for(int j=lo+tid; j<hi; j+=blockDim.x) atomicAdd(&h[fl[j]],1);
  __syncthreads();
  if(tid<16){ base[tid] = h[tid] ? atomicAdd(&ints[64+tid], h[tid]) : 0; h[tid]=0; }
  __syncthreads();
  for(int j=lo+tid; j<hi; j+=blockDim.x){
    int lev = fl[j];
    int pos = base[lev] + atomicAdd(&h[lev],1);
    node_list[pos]=j;
    node_rank[j]=pos-ints[32+lev];
  }
}

// ------ indegree split: REAL edges (1<=fl[s]<fl[tg]) vs CONST edges (count only) --
__global__ void k_indeg(const int* ei, const int* fl, const int* node_rank,
                        const int* ints, int* indeg, int* cnum, int E){
  int i = blockIdx.x*blockDim.x+threadIdx.x;
  int stride = gridDim.x*blockDim.x;
  for(int e=i;e<E;e+=stride){
    int s  = ei[e];
    int tg = ei[E+e];
    int flt = fl[tg];
    int p = ints[32+flt] + node_rank[tg];
    int fls = fl[s];
    if(fls>=1 && fls<flt) atomicAdd(&indeg[p],1);
    else                  atomicAdd(&cnum[p],1);
  }
}

// ---------------- hierarchical exclusive scan of indeg -> row_ptr ----------------
__global__ void k_scan_a(const int* indeg, int* bsum, int N){
  __shared__ int ts[256];
  int b=blockIdx.x, t=threadIdx.x;
  int base=b*SCAN_CHUNK+t*8; int s=0;
  for(int j=0;j<8;j++){ int idx=base+j; if(idx<N) s+=indeg[idx]; }
  ts[t]=s; __syncthreads();
  for(int off=128;off>0;off>>=1){ if(t<off) ts[t]+=ts[t+off]; __syncthreads(); }
  if(t==0) bsum[b]=ts[0];
}
__global__ void k_scan_b(int* bsum, int nb){
  __shared__ int ls[256];
  int t=threadIdx.x;
  int v = (t<nb)? bsum[t]:0; ls[t]=v; __syncthreads();
  for(int off=1;off<256;off<<=1){
    int add = (t>=off)? ls[t-off]:0;
    __syncthreads();
    ls[t]+=add;
    __syncthreads();
  }
  if(t<nb) bsum[t] = ls[t]-v;   // exclusive
}
__global__ void k_scan_c(const int* indeg, const int* bsum, int* row_ptr, int N){
  __shared__ int ts[256];
  int b=blockIdx.x, t=threadIdx.x;
  int base=b*SCAN_CHUNK+t*8;
  int v[8]; int s=0;
  for(int j=0;j<8;j++){ int idx=base+j; v[j]=(idx<N)?indeg[idx]:0; s+=v[j]; }
  ts[t]=s; __syncthreads();
  for(int off=1;off<256;off<<=1){
    int add = (t>=off)? ts[t-off]:0;
    __syncthreads();
    ts[t]+=add;
    __syncthreads();
  }
  int excl = bsum[b] + ((t>0)? ts[t-1]:0);
  for(int j=0;j<8;j++){ int idx=base+j; if(idx<N) row_ptr[idx]=excl; excl+=v[j]; }
}

// ------- place ONLY real edges into CSR -------
__global__ void k_place(const int* ei, const int* fl, const int* node_rank,
                        const int* ints, const int* row_ptr, int* fill,
                        int* edge_src, int E){
  int i = blockIdx.x*blockDim.x+threadIdx.x;
  int stride = gridDim.x*blockDim.x;
  for(int e=i;e<E;e+=stride){
    int s  = ei[e];
    int tg = ei[E+e];
    int flt = fl[tg];
    int fls = fl[s];
    if(fls>=1 && fls<flt){
      int p = ints[32+flt] + node_rank[tg];
      int slot = atomicAdd(&fill[p],1);
      edge_src[row_ptr[p]+slot] = s;
    }
  }
}

// ---------------- out = c0 for LEVEL-0 nodes only (never updated later) ---------
__global__ void k_outc(const int* node_list, const int* ints,
                       float* out, const float* consts){
  int cnt0 = ints[0];
  float c0 = consts[640];
  int i = blockIdx.x*blockDim.x+threadIdx.x;
  int stride = gridDim.x*blockDim.x;
  for(int j=i;j<cnt0;j+=stride) out[node_list[j]]=c0;
}

// ================= persistent kernel: early publish + depth-2 gather =============
// Critical path per level: poll -> gather (2-deep pipelined) -> GEMM1 -> GRU ->
// GEMM2 -> t-store (regs->global, coalesced 64B/16-lane) -> drain -> PUBLISH.
// MLP1/MLP2/out run AFTER publish (off critical path). Publish spread over 8
// counters (blockIdx&7); waiter sums 8 with relaxed backoff polls.
__global__ __launch_bounds__(BLK,1) void k_levels(
    const float* __restrict__ x, const int* __restrict__ node_list,
    const int* __restrict__ row_ptr, const int* __restrict__ indeg,
    const int* __restrict__ cnum, const int* __restrict__ edge_src,
    float* __restrict__ tbuf,
    const unsigned short* __restrict__ wih_h, const unsigned short* __restrict__ wih_l,
    const unsigned short* __restrict__ agg_h, const unsigned short* __restrict__ agg_l,
    const unsigned short* __restrict__ w1_h, const unsigned short* __restrict__ w1_l,
    const float* __restrict__ b_ih, const float* __restrict__ agg_b,
    const float* __restrict__ b1, const float* __restrict__ w2,
    const float* __restrict__ b2, const float* __restrict__ w3,
    const float* __restrict__ b3,
    const float* __restrict__ consts, float* __restrict__ out,
    int* ints, int* lvl_cnt)
{
  __shared__ __align__(16) unsigned char smem[64512];
  unsigned short* Ahi = (unsigned short*)smem;
  unsigned short* Alo = (unsigned short*)(smem + 21504);
  unsigned short* Hhi = (unsigned short*)smem;
  unsigned short* Hlo = (unsigned short*)(smem + 17408);
  float* z1l = (float*)(smem + 43008);
  float* z2l = (float*)(smem + 51456);
  float* w2t = (float*)(smem + 59904);
  float* w3l = (float*)(smem + 64128);
  int*   nlst= (int*)  (smem + 64256);   // 64 node ids

  int tid = threadIdx.x;
  int wv = tid>>6, ln = tid&63, lr = ln&15, lq = ln>>4;
  int cgo = tid&7, nd = tid>>3;    // gather: 8 thr/node, 16 dims each
  int d = wv*16 + lr;              // this lane's output dim (GEMM1/2)
  int mB = wv>>1, nB = wv&1;       // MLP1 sub-tile

  float ghr=consts[256+d], ghz=consts[384+d], ghn=consts[512+d], h0c=consts[d];
  float bir=b_ih[d], biz=b_ih[128+d], bin_=b_ih[256+d], ab2=agg_b[d];
  float b1o = b1[nB*16+lr];
  f32x4 ti[4];
  { const f32x4* c4=(const f32x4*)(consts+128);
    #pragma unroll
    for(int q=0;q<4;q++) ti[q]=c4[cgo*4+q]; }

  // ---- stage small fp32 weights ----
  for(int idx=tid; idx<1024; idx+=BLK){ int j=idx>>5, k=idx&31;  w2t[k*33+j]=w2[idx]; }
  if(tid<32) w3l[tid]=w3[tid];
  __syncthreads();

  int total_tiles = ints[96+NLEV];
  int cslot = (blockIdx.x&7)*16;
  int l = 1;

  for(int T = blockIdx.x; T < total_tiles; T += GRID){
    while(l < NLEV-1 && T >= ints[96+l+1]) l++;
    int cnt  = ints[l];
    int base = ints[32+l];
    int n0 = (T - ints[96+l])*TN;

    // ---- pre-wait staging: node ids + x into A cols 128..159 ----
    if(tid<64) nlst[tid] = ((n0+tid)<cnt)? node_list[base+n0+tid] : 0;
    if(tid<256){
      int i = tid>>2, j = tid&3;
      int gi = n0+i;
      float4 xv = make_float4(0.f,0.f,0.f,0.f);
      if(gi<cnt) xv = ((const float4*)x)[node_list[base+gi]*4 + j];
      float vv[4]={xv.x,xv.y,xv.z,xv.w};
      #pragma unroll
      for(int q=0;q<4;q++){
        unsigned short h=f2bf(vv[q]);
        Ahi[i*AS+128+j*4+q]=h;
        Alo[i*AS+128+j*4+q]=f2bf(vv[q]-bf2f(h));
      }
      #pragma unroll
      for(int q=0;q<4;q++){ Ahi[i*AS+144+j*4+q]=0; Alo[i*AS+144+j*4+q]=0; }
    }

    // ---- wait: previous level fully done (8 spread counters, backoff poll) ----
    if(tid==0 && l>1){
      int need = ints[96+l] - ints[96+l-1];
      if(need>0){
        int it=0;
        for(;;){
          int got=0;
          #pragma unroll
          for(int c=0;c<8;c++)
            got += __hip_atomic_load(&lvl_cnt[(l-1)*128 + c*16], __ATOMIC_RELAXED,
                                     __HIP_MEMORY_SCOPE_AGENT);
          if(got>=need) break;
          if(it<8) __builtin_amdgcn_s_sleep(8);
          else     __builtin_amdgcn_s_sleep(32);
          it++;
        }
      }
    }
    __syncthreads();

    // ---- phase 0: gather (depth-2 pipelined coherent loads) -> bf16 into A ----
    {
      f32x4 a[4];
      int gi = n0+nd;
      if(gi<cnt){
        int p = base+gi;
        int r0 = row_ptr[p], dr = indeg[p];
        float fdc = (float)cnum[p];
        #pragma unroll
        for(int q=0;q<4;q++) a[q] = fdc*ti[q];
        int e=0;
        for(; e+1<dr; e+=2){
          int s0 = edge_src[r0+e], s1 = edge_src[r0+e+1];
          const float* p0 = tbuf + ((long long)s0*128 + cgo*16);
          const float* p1 = tbuf + ((long long)s1*128 + cgo*16);
          f32x4 A0,A1,A2,A3,B0,B1,B2,B3;
          asm volatile(
            "global_load_dwordx4 %0, %8, off sc0 sc1\n\t"
            "global_load_dwordx4 %1, %8, off offset:16 sc0 sc1\n\t"
            "global_load_dwordx4 %2, %8, off offset:32 sc0 sc1\n\t"
            "global_load_dwordx4 %3, %8, off offset:48 sc0 sc1\n\t"
            "global_load_dwordx4 %4, %9, off sc0 sc1\n\t"
            "global_load_dwordx4 %5, %9, off offset:16 sc0 sc1\n\t"
            "global_load_dwordx4 %6, %9, off offset:32 sc0 sc1\n\t"
            "global_load_dwordx4 %7, %9, off offset:48 sc0 sc1"
            : "=&v"(A0),"=&v"(A1),"=&v"(A2),"=&v"(A3),
              "=&v"(B0),"=&v"(B1),"=&v"(B2),"=&v"(B3)
            : "v"(p0), "v"(p1));
          asm volatile("s_waitcnt vmcnt(4)" ::: "memory");
          __builtin_amdgcn_sched_barrier(0);
          a[0]+=A0; a[1]+=A1; a[2]+=A2; a[3]+=A3;
          asm volatile("s_waitcnt vmcnt(0)" ::: "memory");
          __builtin_amdgcn_sched_barrier(0);
          a[0]+=B0; a[1]+=B1; a[2]+=B2; a[3]+=B3;
        }
        if(e<dr){
          int s = edge_src[r0+e];
          const float* sp = tbuf + ((long long)s*128 + cgo*16);
          f32x4 v0,v1,v2,v3;
          row_load_coh(sp, v0,v1,v2,v3);
          a[0]+=v0; a[1]+=v1; a[2]+=v2; a[3]+=v3;
        }
      } else {
        #pragma unroll
        for(int q=0;q<4;q++) a[q]=(f32x4){0.f,0.f,0.f,0.f};
      }
      #pragma unroll
      for(int hf=0; hf<2; hf++){
        short8_t hv, lv;
        #pragma unroll
        for(int j=0;j<8;j++){
          float v = a[hf*2 + (j>>2)][j&3];
          unsigned short h = f2bf(v);
          hv[j]=(short)h; lv[j]=(short)f2bf(v-bf2f(h));
        }
        *(short8_t*)&Ahi[nd*AS + cgo*16 + hf*8] = hv;
        *(short8_t*)&Alo[nd*AS + cgo*16 + hf*8] = lv;
      }
    }
    __syncthreads();   // sync1: A ready

    // ---- phase 1: GEMM1 (bf16x3 MFMA, weights streamed from L2 per kk) ----
    f32x4 Ar[4],Az[4],An[4];
    #pragma unroll
    for(int m=0;m<4;m++){
      Ar[m]=(f32x4){bir,bir,bir,bir};
      Az[m]=(f32x4){biz,biz,biz,biz};
      An[m]=(f32x4){bin_,bin_,bin_,bin_};
    }
    #pragma unroll
    for(int kk=0;kk<5;kk++){
      const unsigned short* wb = wih_h + (long long)d*KP + kk*32 + lq*8;
      const unsigned short* lb = wih_l + (long long)d*KP + kk*32 + lq*8;
      short8_t wrh = *(const short8_t*)wb;
      short8_t wrl = *(const short8_t*)lb;
      short8_t wzh = *(const short8_t*)(wb + (long long)128*KP);
      short8_t wzl = *(const short8_t*)(lb + (long long)128*KP);
      short8_t wnh = *(const short8_t*)(wb + (long long)256*KP);
      short8_t wnl = *(const short8_t*)(lb + (long long)256*KP);
      short8_t ah[4], al[4];
      #pragma unroll
      for(int m=0;m<4;m++){
        int off = (m*16+lr)*AS + kk*32 + lq*8;
        ah[m]=*(const short8_t*)&Ahi[off];
        al[m]=*(const short8_t*)&Alo[off];
      }
      #pragma unroll
      for(int m=0;m<4;m++){
        Ar[m]=__builtin_amdgcn_mfma_f32_16x16x32_bf16(ah[m],wrh,Ar[m],0,0,0);
        Ar[m]=__builtin_amdgcn_mfma_f32_16x16x32_bf16(ah[m],wrl,Ar[m],0,0,0);
        Ar[m]=__builtin_amdgcn_mfma_f32_16x16x32_bf16(al[m],wrh,Ar[m],0,0,0);
        Az[m]=__builtin_amdgcn_mfma_f32_16x16x32_bf16(ah[m],wzh,Az[m],0,0,0);
        Az[m]=__builtin_amdgcn_mfma_f32_16x16x32_bf16(ah[m],wzl,Az[m],0,0,0);
        Az[m]=__builtin_amdgcn_mfma_f32_16x16x32_bf16(al[m],wzh,Az[m],0,0,0);
        An[m]=__builtin_amdgcn_mfma_f32_16x16x32_bf16(ah[m],wnh,An[m],0,0,0);
        An[m]=__builtin_amdgcn_mfma_f32_16x16x32_bf16(ah[m],wnl,An[m],0,0,0);
        An[m]=__builtin_amdgcn_mfma_f32_16x16x32_bf16(al[m],wnh,An[m],0,0,0);
      }
    }
    __syncthreads();   // sync2: all A reads done, H may overwrite

    // ---- phase 2: GRU gates -> H (bf16 hi/lo over A region) ----
    #pragma unroll
    for(int m=0;m<4;m++){
      #pragma unroll
      for(int j=0;j<4;j++){
        float r = sigmoidf_(Ar[m][j] + ghr);
        float z = sigmoidf_(Az[m][j] + ghz);
        float n = tanhf_(An[m][j] + r*ghn);
        float h = (1.f-z)*n + z*h0c;
        int node = m*16 + lq*4 + j;
        unsigned short hb = f2bf(h);
        Hhi[node*HS + d] = hb;
        Hlo[node*HS + d] = f2bf(h - bf2f(hb));
      }
    }
    __syncthreads();   // sync3: H ready

    // ---- phase 3: GEMM2 (t) only; weights streamed from L2 per kk ----
    f32x4 T2[4];
    #pragma unroll
    for(int m=0;m<4;m++) T2[m]=(f32x4){ab2,ab2,ab2,ab2};
    #pragma unroll
    for(int kk=0;kk<4;kk++){
      int ro  = d*DHID + kk*32 + lq*8;
      short8_t agh = *(const short8_t*)&agg_h[ro];
      short8_t agl = *(const short8_t*)&agg_l[ro];
      short8_t hh[4], hl2[4];
      #pragma unroll
      for(int m=0;m<4;m++){
        int off = (m*16+lr)*HS + kk*32 + lq*8;
        hh[m]=*(const short8_t*)&Hhi[off];
        hl2[m]=*(const short8_t*)&Hlo[off];
      }
      #pragma unroll
      for(int m=0;m<4;m++){
        T2[m]=__builtin_amdgcn_mfma_f32_16x16x32_bf16(hh[m], agh,T2[m],0,0,0);
        T2[m]=__builtin_amdgcn_mfma_f32_16x16x32_bf16(hh[m], agl,T2[m],0,0,0);
        T2[m]=__builtin_amdgcn_mfma_f32_16x16x32_bf16(hl2[m],agh,T2[m],0,0,0);
      }
    }

    // ---- t-store directly from regs (64B coalesced per 16-lane group) ----
    #pragma unroll
    for(int m=0;m<4;m++){
      #pragma unroll
      for(int j=0;j<4;j++){
        int node = m*16 + lq*4 + j;
        if(n0+node<cnt){
          float* dp = tbuf + (long long)nlst[node]*128 + d;
          asm volatile("global_store_dword %0, %1, off sc0 sc1"
                       :: "v"(dp), "v"(T2[m][j]) : "memory");
        }
      }
    }
    asm volatile("s_waitcnt vmcnt(0)" ::: "memory");
    __syncthreads();   // sync4: all waves' t-stores at coherence point

    // ---- PUBLISH (early — MLP is off the critical path) ----
    if(tid==0){
      __hip_atomic_fetch_add(&lvl_cnt[l*128 + cslot], 1, __ATOMIC_RELAXED,
                             __HIP_MEMORY_SCOPE_AGENT);
    }

    // ---- MLP1 (MFMA, H still intact in LDS) ----
    f32x4 M1 = (f32x4){b1o,b1o,b1o,b1o};
    #pragma unroll
    for(int kk=0;kk<4;kk++){
      int r1  = (nB*16+lr)*DHID + kk*32 + lq*8;
      short8_t w1h = *(const short8_t*)&w1_h[r1];
      short8_t w1l = *(const short8_t*)&w1_l[r1];
      int off = (mB*16+lr)*HS + kk*32 + lq*8;
      short8_t hh  = *(const short8_t*)&Hhi[off];
      short8_t hl2 = *(const short8_t*)&Hlo[off];
      M1=__builtin_amdgcn_mfma_f32_16x16x32_bf16(hh, w1h,M1,0,0,0);
      M1=__builtin_amdgcn_mfma_f32_16x16x32_bf16(hh, w1l,M1,0,0,0);
      M1=__builtin_amdgcn_mfma_f32_16x16x32_bf16(hl2,w1h,M1,0,0,0);
    }
    #pragma unroll
    for(int j=0;j<4;j++){
      int node = mB*16 + lq*4 + j;
      z1l[node*33 + nB*16+lr] = fmaxf(M1[j],0.f);
    }
    __syncthreads();   // sync5: z1 ready; H reads done

    // ---- MLP2 (VALU) ----
    {
      int ndl = tid>>3, jo = (tid&7)*4;
      float s0=b2[jo], s1=b2[jo+1], s2=b2[jo+2], s3=b2[jo+3];
      #pragma unroll 8
      for(int k=0;k<32;k++){
        float zv = z1l[ndl*33+k];
        s0 += zv*w2t[k*33+jo];
        s1 += zv*w2t[k*33+jo+1];
        s2 += zv*w2t[k*33+jo+2];
        s3 += zv*w2t[k*33+jo+3];
      }
      z2l[ndl*33+jo]   = fmaxf(s0,0.f);
      z2l[ndl*33+jo+1] = fmaxf(s1,0.f);
      z2l[ndl*33+jo+2] = fmaxf(s2,0.f);
      z2l[ndl*33+jo+3] = fmaxf(s3,0.f);
    }
    __syncthreads();   // sync6: z2 ready

    // ---- out store ----
    if(tid<TN){
      if(n0+tid<cnt){
        float s = b3[0];
        #pragma unroll 8
        for(int k=0;k<32;k++) s += z2l[tid*33+k]*w3l[k];
        out[nlst[tid]] = s;
      }
    }
    __syncthreads();   // sync7: protect nlst/z2l before next tile's staging
  }
}

extern "C" void kernel_launch(void* const* d_in, const int* in_sizes, int n_in,
                              void* d_out, int out_size, void* d_ws, size_t ws_size,
                              hipStream_t stream){
  const float* x     = (const float*)d_in[0];
  const int*   ei    = (const int*)  d_in[1];
  const int*   fl    = (const int*)  d_in[2];
  const float* emd_w = (const float*)d_in[4];
  const float* emd_b = (const float*)d_in[5];
  const float* agg_w = (const float*)d_in[6];
  const float* agg_b = (const float*)d_in[7];
  const float* w_ih  = (const float*)d_in[8];
  const float* w_hh  = (const float*)d_in[9];
  const float* b_ih  = (const float*)d_in[10];
  const float* b_hh  = (const float*)d_in[11];
  const float* w1    = (const float*)d_in[12];
  const float* b1    = (const float*)d_in[13];
  const float* w2    = (const float*)d_in[14];
  const float* b2    = (const float*)d_in[15];
  const float* w3    = (const float*)d_in[16];
  const float* b3    = (const float*)d_in[17];
  float* out = (float*)d_out;

  int N = in_sizes[2];
  int E = in_sizes[1]/2;
  int nb = (N + SCAN_CHUNK - 1)/SCAN_CHUNK;

  char* ws = (char*)d_ws;
  float* consts   = (float*)ws;                    // 4 KiB
  int*   ints     = (int*)(ws + 4096);             // 4 KiB (tile_off@96)
  int*   node_list= (int*)(ws + 8192);
  int*   node_rank= node_list + N;
  int*   indeg    = node_rank + N;                 // REAL indegree
  int*   cnum     = indeg + N;                     // const-edge count
  int*   row_ptr  = cnum + N;
  int*   fill     = row_ptr + N;
  int*   bsum     = fill + N;                      // 1024 block sums
  int*   lvl_cnt  = bsum + 1024;                   // 2048 (16 lvls x 8 spread)
  int*   edge_src = lvl_cnt + 2048;                // <= E ints (real edges only)
  size_t off0 = 8192 + ((size_t)6*N + 1024 + 2048 + (size_t)E)*4;
  off0 = (off0 + 255) & ~(size_t)255;
  unsigned short* wih_h = (unsigned short*)(ws + off0);       // 384*160
  unsigned short* wih_l = wih_h + G3*KP;
  unsigned short* agg_h = wih_l + G3*KP;                      // 128*128
  unsigned short* agg_l = agg_h + DHID*DHID;
  unsigned short* w1_h  = agg_l + DHID*DHID;                  // 32*128
  unsigned short* w1_l  = w1_h + 32*DHID;
  size_t off1 = off0 + (size_t)(2*G3*KP + 2*DHID*DHID + 2*32*DHID)*2;
  off1 = (off1 + 255) & ~(size_t)255;
  float* tbuf = (float*)(ws + off1);               // N*128 floats, never pre-initialized
  size_t need = off1 + (size_t)N*128*4;
  if(ws_size < need) return;

  k_zero0  <<<512,256,0,stream>>>(ints, lvl_cnt, indeg, cnum, fill, N);
  k_init   <<<1,128,0,stream>>>(emd_w,emd_b,agg_w,agg_b,w_hh,b_hh,w1,b1,w2,b2,w3,b3,consts);
  k_wprep  <<<256,256,0,stream>>>(w_ih,agg_w,w1,wih_h,wih_l,agg_h,agg_l,w1_h,w1_l);
  k_count  <<<512,256,0,stream>>>(fl,N,ints);
  k_prefix <<<1,1,0,stream>>>(ints);
  k_build  <<<512,256,0,stream>>>(fl,N,ints,node_list,node_rank);
  k_indeg  <<<1024,256,0,stream>>>(ei,fl,node_rank,ints,indeg,cnum,E);
  k_scan_a <<<nb,256,0,stream>>>(indeg,bsum,N);
  k_scan_b <<<1,256,0,stream>>>(bsum,nb);
  k_scan_c <<<nb,256,0,stream>>>(indeg,bsum,row_ptr,N);
  k_place  <<<1024,256,0,stream>>>(ei,fl,node_rank,ints,row_ptr,fill,edge_src,E);
  k_outc   <<<256,256,0,stream>>>(node_list,ints,out,consts);
  k_levels <<<GRID,BLK,0,stream>>>(x,node_list,row_ptr,indeg,cnum,edge_src,tbuf,
                                   wih_h,wih_l,agg_h,agg_l,w1_h,w1_l,
                                   b_ih,agg_b,b1,w2,b2,w3,b3,
                                   consts,out,ints,lvl_cnt);
}